// Round 2
// baseline (507.620 us; speedup 1.0000x reference)
//
#include <hip/hip_runtime.h>
#include <hip/hip_bf16.h>

// Problem constants
#define BATCH 64
#define NATOM 120
#define NNB 10
#define NBOND 250
#define AFDIM 82
#define BFDIM 6
#define HREAL 300
#define HP 320            // padded H
#define NCT32 10          // 10 col-tiles of 32 -> 320
#define MA (BATCH*NATOM)  // 7680
#define MB (BATCH*NBOND)  // 16000
#define LSTR 328          // u16 stride of LDS activation rows (656 B = 41*16 -> conflict-reduced, b128-aligned)

typedef short short8 __attribute__((ext_vector_type(8)));   // 8 bf16
typedef float f32x16 __attribute__((ext_vector_type(16)));  // 32x32 MFMA accumulator
typedef unsigned int u32;
typedef u32 u32x4 __attribute__((ext_vector_type(4)));
typedef unsigned short u16;
typedef unsigned char u8;

__device__ __forceinline__ float bflo(u32 v) { return __builtin_bit_cast(float, v << 16); }
__device__ __forceinline__ float bfhi(u32 v) { return __builtin_bit_cast(float, v & 0xffff0000u); }
__device__ __forceinline__ u16 f2bf(float f) {
    __hip_bfloat16 h = __float2bfloat16(f);
    return __builtin_bit_cast(u16, h);
}
__device__ __forceinline__ int imin(int a, int b) { return a < b ? a : b; }

// ================= prep: fp32->bf16 convs + all 8 weight packs in ONE launch =================
struct PackJob { const float* W; short8* dst; int Kreal, KT, KTfull, ktOff, blk0; };
struct Prep {
    const float* a1src; __hip_bfloat16* a1dst;   // [MA][82] -> [MA][96]
    const float* bsrc;  __hip_bfloat16* bdst;    // [MB][6]  -> [MB][32]
    PackJob j[8];
};

#define CONV1_BLKS 2880   // MA*96/256
#define CONV2_BLKS 2000   // MB*32/256
#define PACK_BASE  (CONV1_BLKS + CONV2_BLKS)
#define PACK_BLKS  275
#define PREP_BLKS  (PACK_BASE + PACK_BLKS)   // 5155

__global__ __launch_bounds__(256) void prep_all(Prep cfg) {
    const int bid = blockIdx.x;
    const int tid = threadIdx.x;
    if (bid < CONV1_BLKS) {
        int id = bid * 256 + tid;                 // exact multiple
        int r = id / 96, c = id - r * 96;
        float f = (c < AFDIM) ? cfg.a1src[(size_t)r * AFDIM + c] : 0.f;
        cfg.a1dst[id] = __float2bfloat16(f);
    } else if (bid < PACK_BASE) {
        int id = (bid - CONV1_BLKS) * 256 + tid;  // exact multiple
        int r = id >> 5, c = id & 31;
        float f = (c < BFDIM) ? cfg.bsrc[(size_t)r * BFDIM + c] : 0.f;
        cfg.bdst[id] = __float2bfloat16(f);
    } else {
        const int pid = bid - PACK_BASE;
        int ji = 0;
#pragma unroll
        for (int i = 1; i < 8; ++i) if (pid >= cfg.j[i].blk0) ji = i;
        const PackJob J = cfg.j[ji];
        int id = (pid - J.blk0) * 256 + tid;
        int n = NCT32 * J.KT * 64;
        if (id >= n) return;
        int lane = id & 63;
        int kt = (id >> 6) % J.KT;
        int ct = id / (J.KT * 64);
        int col = ct * 32 + (lane & 31);
        int kbase = kt * 16 + (lane >> 5) * 8;
        short8 v;
#pragma unroll
        for (int jj = 0; jj < 8; ++jj) {
            int k = kbase + jj;
            float f = (k < J.Kreal && col < HREAL) ? J.W[(size_t)k * HREAL + col] : 0.f;
            v[jj] = (short)f2bf(f);
        }
        J.dst[(size_t)(ct * J.KTfull + J.ktOff + kt) * 64 + lane] = v;
    }
}

// ================= fused whole-network kernel: one block per batch =================
struct FusedArgs {
    const __hip_bfloat16 *A1b, *bondb;
    const short8 *pW1, *pWbd, *pWnei, *pWga, *pWfd;
    const float *b_gn, *b_ga;
    const int *ag, *bg, *mn, *ma;
    __hip_bfloat16 *bondgc, *bnb, *nei1, *nei2, *selfF;
    float *out;
};

// A from LDS (20 kt = K 320 slice), 5 cts accumulated. Weight index stride KTF, offset KTOFF.
template<int KTF, int KTOFF>
__device__ __forceinline__ void gemm5_lds(const u16* AFL, int arow, int koff,
                                          const short8* W, int ct0, int lane,
                                          f32x16 acc[5]) {
#pragma unroll
    for (int h = 0; h < 2; ++h) {
        short8 a[10];
#pragma unroll
        for (int kt = 0; kt < 10; ++kt)
            a[kt] = *reinterpret_cast<const short8*>(&AFL[arow * LSTR + (h * 10 + kt) * 16 + koff]);
#pragma unroll
        for (int kt = 0; kt < 10; ++kt)
#pragma unroll
            for (int c = 0; c < 5; ++c)
                acc[c] = __builtin_amdgcn_mfma_f32_32x32x16_bf16(
                    a[kt], W[((size_t)(ct0 + c) * KTF + KTOFF + h * 10 + kt) * 64 + lane], acc[c], 0, 0, 0);
    }
}

// A from global (row base pointer incl. koff), 20 kt, 5 cts.
template<int KTF, int KTOFF>
__device__ __forceinline__ void gemm5_glob(const __hip_bfloat16* Abase,
                                           const short8* W, int ct0, int lane,
                                           f32x16 acc[5]) {
#pragma unroll
    for (int h = 0; h < 2; ++h) {
        short8 a[10];
#pragma unroll
        for (int kt = 0; kt < 10; ++kt)
            a[kt] = *reinterpret_cast<const short8*>(Abase + (h * 10 + kt) * 16);
#pragma unroll
        for (int kt = 0; kt < 10; ++kt)
#pragma unroll
            for (int c = 0; c < 5; ++c)
                acc[c] = __builtin_amdgcn_mfma_f32_32x32x16_bf16(
                    a[kt], W[((size_t)(ct0 + c) * KTF + KTOFF + h * 10 + kt) * 64 + lane], acc[c], 0, 0, 0);
    }
}

#define ZERO5(acc) { _Pragma("unroll") for (int c_ = 0; c_ < 5; ++c_) { _Pragma("unroll") for (int r_ = 0; r_ < 16; ++r_) acc[c_][r_] = 0.f; } }

__global__ __launch_bounds__(512)
void fused_net(FusedArgs A) {
    extern __shared__ u16 lds[];
    u16* AFL = lds;                       // [120][LSTR]  atom features (persistent)
    u16* TL  = lds + 120 * LSTR;          // [120][LSTR]  T / A2f scratch
    u8*  agL = (u8*)(lds + 2 * 120 * LSTR);
    u8*  bgL = agL + NATOM * NNB;
    u16* mnL = (u16*)(bgL + NATOM * NNB); // [120] neighbor-mask bits
    u8*  maL = (u8*)(mnL + NATOM);        // [120] atom mask

    const int b    = blockIdx.x;
    const int tid  = threadIdx.x;
    const int lane = tid & 63;
    const int w    = tid >> 6;            // 0..7
    const int rt   = w >> 1;              // row-tile 0..3 (atoms)
    const int cg   = w & 1;               // ct-group 0..1
    const int lrow = lane & 31;
    const int koff = (lane >> 5) * 8;
    const int r1a  = imin(rt * 32 + lrow, NATOM - 1);   // clamped batch-relative atom row
    const int ct0  = cg * 5;

    // ---- P0: indices -> LDS ----
    for (int i = tid; i < NATOM * NNB; i += 512) {
        agL[i] = (u8)A.ag[b * NATOM * NNB + i];
        bgL[i] = (u8)A.bg[b * NATOM * NNB + i];
    }
    for (int i = tid; i < NATOM; i += 512) {
        u32 m = 0;
#pragma unroll
        for (int j = 0; j < NNB; ++j)
            if (A.mn[(b * NATOM + i) * NNB + j]) m |= 1u << j;
        mnL[i] = (u16)m;
        maL[i] = (u8)(A.ma[b * NATOM + i] != 0);
    }

    // ---- P1a: bond dual GEMM -> bondgc (+bias), bnb (global) ----
    {
        const int r1 = imin(w * 32 + lrow, NBOND - 1);
        const __hip_bfloat16* arow = A.bondb + ((size_t)(b * NBOND + r1)) * 32 + koff;
        short8 a0 = *reinterpret_cast<const short8*>(arow);
        short8 a1 = *reinterpret_cast<const short8*>(arow + 16);
#pragma unroll
        for (int cq = 0; cq < 5; ++cq) {
            f32x16 acc[4];
#pragma unroll
            for (int c = 0; c < 4; ++c) {
#pragma unroll
                for (int r = 0; r < 16; ++r) acc[c][r] = 0.f;
            }
#pragma unroll
            for (int c = 0; c < 4; ++c) {
                const int ct = cq * 4 + c;
                const short8* wp = A.pWbd + ((size_t)ct * 2) * 64 + lane;
                acc[c] = __builtin_amdgcn_mfma_f32_32x32x16_bf16(a0, wp[0],  acc[c], 0, 0, 0);
                acc[c] = __builtin_amdgcn_mfma_f32_32x32x16_bf16(a1, wp[64], acc[c], 0, 0, 0);
            }
#pragma unroll
            for (int c = 0; c < 4; ++c) {
                const int ct = cq * 4 + c;
                const int col = ((ct >= NCT32) ? ct * 32 - HP : ct * 32) + lrow;
                __hip_bfloat16* op = (ct >= NCT32) ? A.bnb : A.bondgc;
                const float bb = (ct < NCT32 && col < HREAL) ? A.b_gn[col] : 0.f;
#pragma unroll
                for (int r = 0; r < 16; ++r) {
                    const int row = w * 32 + (r & 3) + 8 * (r >> 2) + 4 * (lane >> 5);
                    if (row < NBOND)
                        op[((size_t)(b * NBOND + row)) * HP + col] = __float2bfloat16(acc[c][r] + bb);
                }
            }
        }
    }

    // ---- P1b: fc1 -> AFL (relu) ----
    {
        const __hip_bfloat16* arow = A.A1b + ((size_t)(b * NATOM + r1a)) * 96 + koff;
        short8 a[6];
#pragma unroll
        for (int kt = 0; kt < 6; ++kt) a[kt] = *reinterpret_cast<const short8*>(arow + kt * 16);
        f32x16 acc[5];
        ZERO5(acc);
#pragma unroll
        for (int kt = 0; kt < 6; ++kt)
#pragma unroll
            for (int c = 0; c < 5; ++c)
                acc[c] = __builtin_amdgcn_mfma_f32_32x32x16_bf16(
                    a[kt], A.pW1[((size_t)(ct0 + c) * 6 + kt) * 64 + lane], acc[c], 0, 0, 0);
#pragma unroll
        for (int r = 0; r < 16; ++r) {
            const int row = rt * 32 + (r & 3) + 8 * (r >> 2) + 4 * (lane >> 5);
            if (row < NATOM) {
#pragma unroll
                for (int c = 0; c < 5; ++c)
                    AFL[row * LSTR + (ct0 + c) * 32 + lrow] = f2bf(fmaxf(acc[c][r], 0.f));
            }
        }
    }
    __syncthreads();

    // ---- graph-conv iterations ----
    __hip_bfloat16* const neibufs[2] = {A.nei1, A.nei2};
    for (int it = 0; it < 2; ++it) {
        // nu: TL = AFL @ W_nei (no bias/relu)
        {
            f32x16 acc[5];
            ZERO5(acc);
            gemm5_lds<20, 0>(AFL, r1a, koff, A.pWnei, ct0, lane, acc);
#pragma unroll
            for (int r = 0; r < 16; ++r) {
                const int row = rt * 32 + (r & 3) + 8 * (r >> 2) + 4 * (lane >> 5);
                if (row < NATOM) {
#pragma unroll
                    for (int c = 0; c < 5; ++c)
                        TL[row * LSTR + (ct0 + c) * 32 + lrow] = f2bf(acc[c][r]);
                }
            }
        }
        __syncthreads();
        // gather: nei = sum_j relu(T[ag] + bondgc[bg])  -> global nei buffer
        {
            __hip_bfloat16* nd = neibufs[it];
            const u32* bgc = reinterpret_cast<const u32*>(A.bondgc);
#pragma unroll
            for (int p = 0; p < 10; ++p) {
                const int id = p * 512 + tid;
                if (id < NATOM * 40) {
                    const int row = id / 40, ch = id - row * 40;   // 16B chunk
                    const u32 mb = mnL[row];
                    float lo[4] = {0.f, 0.f, 0.f, 0.f}, hi[4] = {0.f, 0.f, 0.f, 0.f};
#pragma unroll
                    for (int j = 0; j < NNB; ++j) {
                        if ((mb >> j) & 1) {
                            const int a  = agL[row * NNB + j];
                            const int bo = bgL[row * NNB + j];
                            u32x4 ta = *reinterpret_cast<const u32x4*>(&TL[a * LSTR + ch * 8]);
                            u32x4 tb = *reinterpret_cast<const u32x4*>(bgc + ((size_t)(b * NBOND + bo)) * (HP / 2) + ch * 4);
#pragma unroll
                            for (int q = 0; q < 4; ++q) {
                                lo[q] += fmaxf(bflo(ta[q]) + bflo(tb[q]), 0.f);
                                hi[q] += fmaxf(bfhi(ta[q]) + bfhi(tb[q]), 0.f);
                            }
                        }
                    }
                    u32x4 o;
#pragma unroll
                    for (int q = 0; q < 4; ++q) o[q] = (u32)f2bf(lo[q]) | ((u32)f2bf(hi[q]) << 16);
                    *reinterpret_cast<u32x4*>(reinterpret_cast<u32*>(nd) + ((size_t)(b * NATOM + row)) * (HP / 2) + ch * 4) = o;
                }
            }
        }
        __syncthreads();
        // bot: AFL = relu([AFL | nei] @ W_gc_atom + b)
        {
            f32x16 acc[5];
            ZERO5(acc);
            gemm5_lds<40, 0>(AFL, r1a, koff, A.pWga, ct0, lane, acc);
            gemm5_glob<40, 20>(neibufs[it] + ((size_t)(b * NATOM + r1a)) * HP + koff, A.pWga, ct0, lane, acc);
            __syncthreads();   // all AFL reads done before overwrite
#pragma unroll
            for (int c = 0; c < 5; ++c) {
                const int col = (ct0 + c) * 32 + lrow;
                const float bb = (col < HREAL) ? A.b_ga[col] : 0.f;
#pragma unroll
                for (int r = 0; r < 16; ++r) {
                    const int row = rt * 32 + (r & 3) + 8 * (r >> 2) + 4 * (lane >> 5);
                    if (row < NATOM)
                        AFL[row * LSTR + col] = f2bf(fmaxf(acc[c][r] + bb, 0.f));
                }
            }
        }
        __syncthreads();
    }

    // ---- final layer ----
    // selfF = AFL @ W_fc2 -> global
    {
        f32x16 acc[5];
        ZERO5(acc);
        gemm5_lds<20, 0>(AFL, r1a, koff, A.pWfd, ct0, lane, acc);
#pragma unroll
        for (int r = 0; r < 16; ++r) {
            const int row = rt * 32 + (r & 3) + 8 * (r >> 2) + 4 * (lane >> 5);
            if (row < NATOM) {
#pragma unroll
                for (int c = 0; c < 5; ++c)
                    A.selfF[((size_t)(b * NATOM + row)) * HP + (ct0 + c) * 32 + lrow] = __float2bfloat16(acc[c][r]);
            }
        }
    }
    // A2f = AFL @ W_fc2a -> TL
    {
        f32x16 acc[5];
        ZERO5(acc);
        gemm5_lds<20, 0>(AFL, r1a, koff, A.pWfd, 10 + ct0, lane, acc);
#pragma unroll
        for (int r = 0; r < 16; ++r) {
            const int row = rt * 32 + (r & 3) + 8 * (r >> 2) + 4 * (lane >> 5);
            if (row < NATOM) {
#pragma unroll
                for (int c = 0; c < 5; ++c)
                    TL[row * LSTR + (ct0 + c) * 32 + lrow] = f2bf(acc[c][r]);
            }
        }
    }
    __syncthreads();
    // final_bf: out = maska ? selfF * sum_j mask (A2f[ag]*bnb[bg]) : 0
    {
        const u32* bnbp = reinterpret_cast<const u32*>(A.bnb);
        const u32* sfp  = reinterpret_cast<const u32*>(A.selfF);
#pragma unroll
        for (int p = 0; p < 36; ++p) {
            const int id = p * 512 + tid;
            if (id < NATOM * 150) {
                const int row = id / 150, tc = id - row * 150;
                const u32 mb = mnL[row];
                float lo = 0.f, hi = 0.f;
#pragma unroll
                for (int j = 0; j < NNB; ++j) {
                    if ((mb >> j) & 1) {
                        const int a  = agL[row * NNB + j];
                        const int bo = bgL[row * NNB + j];
                        u32 va = *reinterpret_cast<const u32*>(&TL[a * LSTR + tc * 2]);
                        u32 vb = bnbp[((size_t)(b * NBOND + bo)) * (HP / 2) + tc];
                        lo += bflo(va) * bflo(vb);
                        hi += bfhi(va) * bfhi(vb);
                    }
                }
                float2 r2;
                r2.x = 0.f; r2.y = 0.f;
                if (maL[row]) {
                    u32 s = sfp[((size_t)(b * NATOM + row)) * (HP / 2) + tc];
                    r2.x = bflo(s) * lo;
                    r2.y = bfhi(s) * hi;
                }
                *reinterpret_cast<float2*>(A.out + ((size_t)(b * NATOM + row)) * HREAL + 2 * tc) = r2;
            }
        }
    }
}

#define LDS_BYTES (2*120*LSTR*2 + NATOM*NNB*2 + NATOM*2 + NATOM)   // 157440 + 2400 + 240 + 120 = 160200

extern "C" void kernel_launch(void* const* d_in, const int* in_sizes, int n_in,
                              void* d_out, int out_size, void* d_ws, size_t ws_size,
                              hipStream_t stream) {
    const float* A1        = (const float*)d_in[0];
    const float* bond      = (const float*)d_in[1];
    const int*   ag        = (const int*)d_in[2];
    const int*   bg        = (const int*)d_in[3];
    const int*   maskn     = (const int*)d_in[6];
    const int*   maska     = (const int*)d_in[7];
    const float* W_fc1     = (const float*)d_in[8];
    const float* W_gc_nei  = (const float*)d_in[9];
    const float* b_gc_nei  = (const float*)d_in[10];
    const float* W_gc_atom = (const float*)d_in[11];
    const float* b_gc_atom = (const float*)d_in[12];
    const float* W_fc2a    = (const float*)d_in[13];
    const float* W_fc2b    = (const float*)d_in[14];
    const float* W_fc2     = (const float*)d_in[15];
    float* out = (float*)d_out;

    // ---- workspace carve-up ----
    char* p = (char*)d_ws;
    auto alloc = [&](size_t bytes) { char* r = p; p += (bytes + 63) & ~(size_t)63; return r; };
    __hip_bfloat16* A1b    = (__hip_bfloat16*)alloc((size_t)MA * 96 * 2);
    __hip_bfloat16* bondb  = (__hip_bfloat16*)alloc((size_t)MB * 32 * 2);
    __hip_bfloat16* bondgc = (__hip_bfloat16*)alloc((size_t)MB * HP * 2);
    __hip_bfloat16* bnb    = (__hip_bfloat16*)alloc((size_t)MB * HP * 2);
    __hip_bfloat16* nei1   = (__hip_bfloat16*)alloc((size_t)MA * HP * 2);
    __hip_bfloat16* nei2   = (__hip_bfloat16*)alloc((size_t)MA * HP * 2);
    __hip_bfloat16* selfF  = (__hip_bfloat16*)alloc((size_t)MA * HP * 2);
    short8* pW1  = (short8*)alloc((size_t)NCT32 * 6  * 64 * 16);        // fc1          K=96
    short8* pWnei= (short8*)alloc((size_t)NCT32 * 20 * 64 * 16);        // gc_nei[:H]   K=320
    short8* pWga = (short8*)alloc((size_t)NCT32 * 40 * 64 * 16);        // gc_atom cat  K=640
    short8* pWbd = (short8*)alloc((size_t)2 * NCT32 * 2 * 64 * 16);     // bond dual    K=32, 20 ct
    short8* pWfd = (short8*)alloc((size_t)2 * NCT32 * 20 * 64 * 16);    // fc2 | fc2a   K=320, 20 ct

    // ---- prep: convs + packs in one launch ----
    Prep cfg;
    cfg.a1src = A1;   cfg.a1dst = A1b;
    cfg.bsrc  = bond; cfg.bdst  = bondb;
    //           W                                  dst                          Kreal  KT KTf off blk0
    cfg.j[0] = { W_fc1,                             pW1,                         AFDIM, 6,  6,  0,   0 };
    cfg.j[1] = { W_gc_nei,                          pWnei,                       HREAL, 20, 20, 0,  15 };
    cfg.j[2] = { W_gc_atom,                         pWga,                        HREAL, 20, 40, 0,  65 };
    cfg.j[3] = { W_gc_atom + (size_t)HREAL * HREAL, pWga,                        HREAL, 20, 40, 20, 115 };
    cfg.j[4] = { W_gc_nei + (size_t)HREAL * HREAL,  pWbd,                        BFDIM, 2,  2,  0, 165 };
    cfg.j[5] = { W_fc2b,                            pWbd + (size_t)NCT32*2*64,   BFDIM, 2,  2,  0, 170 };
    cfg.j[6] = { W_fc2,                             pWfd,                        HREAL, 20, 20, 0, 175 };
    cfg.j[7] = { W_fc2a,                            pWfd + (size_t)NCT32*20*64,  HREAL, 20, 20, 0, 225 };
    prep_all<<<dim3(PREP_BLKS), dim3(256), 0, stream>>>(cfg);

    // ---- fused whole-network kernel: 1 block per batch, everything LDS-resident ----
    static int attr_done = 0;
    if (!attr_done) {
        hipFuncSetAttribute((const void*)fused_net, hipFuncAttributeMaxDynamicSharedMemorySize, LDS_BYTES);
        attr_done = 1;
    }
    FusedArgs fa;
    fa.A1b = A1b; fa.bondb = bondb;
    fa.pW1 = pW1; fa.pWbd = pWbd; fa.pWnei = pWnei; fa.pWga = pWga; fa.pWfd = pWfd;
    fa.b_gn = b_gc_nei; fa.b_ga = b_gc_atom;
    fa.ag = ag; fa.bg = bg; fa.mn = maskn; fa.ma = maska;
    fa.bondgc = bondgc; fa.bnb = bnb; fa.nei1 = nei1; fa.nei2 = nei2; fa.selfF = selfF;
    fa.out = out;
    fused_net<<<dim3(BATCH), dim3(512), LDS_BYTES, stream>>>(fa);
}

// Round 3
// 216.697 us; speedup vs baseline: 2.3425x; 2.3425x over previous
//
#include <hip/hip_runtime.h>
#include <hip/hip_bf16.h>

// Problem constants
#define BATCH 64
#define NATOM 120
#define NNB 10
#define NBOND 250
#define AFDIM 82
#define BFDIM 6
#define HREAL 300
#define HP 320            // padded H (bf16 activation row stride); pad cols hold exact 0
#define NCT32 10          // 10 col-tiles of 32 -> 320
#define MA (BATCH*NATOM)  // 7680  (= 120 * 64)
#define MB (BATCH*NBOND)  // 16000 (= 250 * 64)

typedef short short8 __attribute__((ext_vector_type(8)));   // 8 bf16 (4 VGPRs)
typedef float f32x16 __attribute__((ext_vector_type(16)));  // 32x32 MFMA accumulator
typedef unsigned int u32;
typedef unsigned short u16;

__device__ __forceinline__ float bflo(u32 v) { return __builtin_bit_cast(float, v << 16); }
__device__ __forceinline__ float bfhi(u32 v) { return __builtin_bit_cast(float, v & 0xffff0000u); }
__device__ __forceinline__ u16 f2bf(float f) {
    __hip_bfloat16 h = __float2bfloat16(f);
    return __builtin_bit_cast(u16, h);
}

// ================= prep: fp32->bf16 convs + all 8 weight packs in ONE launch =================
struct PackJob { const float* W; short8* dst; int Kreal, KT, KTfull, ktOff, blk0; };
struct Prep {
    const float* a1src; __hip_bfloat16* a1dst;   // [MA][82] -> [MA][96]
    const float* bsrc;  __hip_bfloat16* bdst;    // [MB][6]  -> [MB][32]
    PackJob j[8];
};

#define CONV1_BLKS 2880   // MA*96/256
#define CONV2_BLKS 2000   // MB*32/256
#define PACK_BASE  (CONV1_BLKS + CONV2_BLKS)
#define PACK_BLKS  275
#define PREP_BLKS  (PACK_BASE + PACK_BLKS)   // 5155

__global__ __launch_bounds__(256) void prep_all(Prep cfg) {
    const int bid = blockIdx.x;
    const int tid = threadIdx.x;
    if (bid < CONV1_BLKS) {
        int id = bid * 256 + tid;                 // exact multiple
        int r = id / 96, c = id - r * 96;
        float f = (c < AFDIM) ? cfg.a1src[(size_t)r * AFDIM + c] : 0.f;
        cfg.a1dst[id] = __float2bfloat16(f);
    } else if (bid < PACK_BASE) {
        int id = (bid - CONV1_BLKS) * 256 + tid;  // exact multiple
        int r = id >> 5, c = id & 31;
        float f = (c < BFDIM) ? cfg.bsrc[(size_t)r * BFDIM + c] : 0.f;
        cfg.bdst[id] = __float2bfloat16(f);
    } else {
        const int pid = bid - PACK_BASE;
        int ji = 0;
#pragma unroll
        for (int i = 1; i < 8; ++i) if (pid >= cfg.j[i].blk0) ji = i;
        const PackJob J = cfg.j[ji];
        int id = (pid - J.blk0) * 256 + tid;
        int n = NCT32 * J.KT * 64;
        if (id >= n) return;
        int lane = id & 63;
        int kt = (id >> 6) % J.KT;
        int ct = id / (J.KT * 64);
        int col = ct * 32 + (lane & 31);
        int kbase = kt * 16 + (lane >> 5) * 8;
        short8 v;
#pragma unroll
        for (int jj = 0; jj < 8; ++jj) {
            int k = kbase + jj;
            float f = (k < J.Kreal && col < HREAL) ? J.W[(size_t)k * HREAL + col] : 0.f;
            v[jj] = (short)f2bf(f);
        }
        J.dst[(size_t)(ct * J.KTfull + J.ktOff + kt) * 64 + lane] = v;
    }
}

// ================= MFMA GEMM (32x32x16), block = 64 rows x 320 cols, 4 waves =================
// wave w: rt = w>>1 (32-row half), cg = w&1 (5-ct group). 5 accumulators per wave.
// 4-deep software-pipelined prefetch ring on A-fragments and W-fragments (all reg-resident,
// indices compile-time after full unroll). __launch_bounds__(256,1) -> VGPR cap 512, no spill.
// A = [A1 | A2] split at kt==KT1 (row strides KT1*16 / (KT-KT1)*16).
// ct < NCT32 -> out0, else out1 (col - HP). bias0/bias1 optional (nullptr -> 0).
template<int KT, int KT1, bool RELU>
__global__ __launch_bounds__(256, 1)
void gemm64(const __hip_bfloat16* __restrict__ A1,
            const __hip_bfloat16* __restrict__ A2,
            const short8* __restrict__ Wp,
            const float* __restrict__ bias0,
            const float* __restrict__ bias1,
            __hip_bfloat16* __restrict__ out0,
            __hip_bfloat16* __restrict__ out1) {
    const int lane = threadIdx.x & 63;
    const int w    = threadIdx.x >> 6;        // 0..3
    const int rt   = w >> 1;                  // 0..1
    const int cg   = w & 1;                   // 0..1
    const int m0   = blockIdx.x * 64 + rt * 32;
    const int ct0  = blockIdx.y * 10 + cg * 5;
    const int r1   = m0 + (lane & 31);
    const int koff = (lane >> 5) * 8;

    constexpr int S1 = KT1 * 16;
    constexpr int S2 = (KT - KT1) * 16;
    constexpr int PF = (KT >= 4) ? 4 : KT;    // prefetch ring depth

    const short8* wbase = Wp + (size_t)ct0 * KT * 64 + lane;

    auto loadA = [&](int g) -> short8 {
        if (g < KT1)
            return *reinterpret_cast<const short8*>(A1 + (size_t)r1 * S1 + g * 16 + koff);
        else
            return *reinterpret_cast<const short8*>(A2 + (size_t)r1 * S2 + (g - KT1) * 16 + koff);
    };

    f32x16 acc[5];
#pragma unroll
    for (int c = 0; c < 5; ++c) {
#pragma unroll
        for (int r = 0; r < 16; ++r) acc[c][r] = 0.f;
    }

    short8 ar[PF];
    short8 wr[PF][5];
#pragma unroll
    for (int i = 0; i < PF; ++i) {
        ar[i] = loadA(i);
#pragma unroll
        for (int c = 0; c < 5; ++c) wr[i][c] = wbase[((size_t)c * KT + i) * 64];
    }

#pragma unroll
    for (int kt = 0; kt < KT; ++kt) {
        const int slot = kt % PF;             // compile-time after unroll
        short8 a = ar[slot];
        short8 wv[5];
#pragma unroll
        for (int c = 0; c < 5; ++c) wv[c] = wr[slot][c];
        const int nk = kt + PF;
        if (nk < KT) {                        // compile-time guard after unroll
            ar[slot] = loadA(nk);
#pragma unroll
            for (int c = 0; c < 5; ++c) wr[slot][c] = wbase[((size_t)c * KT + nk) * 64];
        }
#pragma unroll
        for (int c = 0; c < 5; ++c)
            acc[c] = __builtin_amdgcn_mfma_f32_32x32x16_bf16(a, wv[c], acc[c], 0, 0, 0);
    }

    // ---- epilogue ----
#pragma unroll
    for (int c = 0; c < 5; ++c) {
        const int ct = ct0 + c;
        const bool second = (ct >= NCT32);
        const int colb = second ? ct * 32 - HP : ct * 32;
        const int col = colb + (lane & 31);
        __hip_bfloat16* op = second ? out1 : out0;
        const float* bp = second ? bias1 : bias0;
        const float bb = (bp && col < HREAL) ? bp[col] : 0.f;
#pragma unroll
        for (int r = 0; r < 16; ++r) {
            const int row = m0 + (r & 3) + 8 * (r >> 2) + 4 * (lane >> 5);
            float v = acc[c][r] + bb;
            if (RELU) v = fmaxf(v, 0.f);
            op[(size_t)row * HP + col] = __float2bfloat16(v);
        }
    }
}

// ================= gather + relu + masked sum (2 rows per block) =================
__global__ __launch_bounds__(320)
void gather_relu_sum_bf(const u32* __restrict__ T,       // [MA][HP/2]
                        const u32* __restrict__ BG,      // [MB][HP/2]
                        const int* __restrict__ ag,
                        const int* __restrict__ bg,
                        const int* __restrict__ maskn,
                        u32* __restrict__ nei) {
    const int bn = blockIdx.x * 2 + threadIdx.x / 160;
    const int t  = threadIdx.x % 160;
    const int b  = bn / NATOM;
    const int base = bn * NNB;
    float lo = 0.f, hi = 0.f;
#pragma unroll
    for (int j = 0; j < NNB; ++j) {
        if (maskn[base + j]) {
            const int a  = ag[base + j];
            const int bo = bg[base + j];
            u32 ta = T[(size_t)(b * NATOM + a) * (HP / 2) + t];
            u32 tb = BG[(size_t)(b * NBOND + bo) * (HP / 2) + t];
            lo += fmaxf(bflo(ta) + bflo(tb), 0.f);
            hi += fmaxf(bfhi(ta) + bfhi(tb), 0.f);
        }
    }
    nei[(size_t)bn * (HP / 2) + t] = (u32)f2bf(lo) | ((u32)f2bf(hi) << 16);
}

// ================= final: out = mask_atoms ? selfF * sum_j(mask ? A2f[ag]*bnb[bg] : 0) : 0 =================
__global__ __launch_bounds__(320)
void final_bf(const u32* __restrict__ A2f,
              const u32* __restrict__ bnb,
              const u32* __restrict__ selfF,
              const int* __restrict__ ag,
              const int* __restrict__ bg,
              const int* __restrict__ maskn,
              const int* __restrict__ maska,
              float* __restrict__ out) {      // [MA][300] fp32
    const int bn = blockIdx.x * 2 + threadIdx.x / 160;
    const int t  = threadIdx.x % 160;
    if (t >= 150) return;
    const int b  = bn / NATOM;
    const int base = bn * NNB;
    float lo = 0.f, hi = 0.f;
#pragma unroll
    for (int j = 0; j < NNB; ++j) {
        if (maskn[base + j]) {
            const int a  = ag[base + j];
            const int bo = bg[base + j];
            u32 va = A2f[(size_t)(b * NATOM + a) * (HP / 2) + t];
            u32 vb = bnb[(size_t)(b * NBOND + bo) * (HP / 2) + t];
            lo += bflo(va) * bflo(vb);
            hi += bfhi(va) * bfhi(vb);
        }
    }
    float2 r;
    if (maska[bn]) {
        u32 s = selfF[(size_t)bn * (HP / 2) + t];
        r.x = bflo(s) * lo;
        r.y = bfhi(s) * hi;
    } else {
        r.x = 0.f; r.y = 0.f;
    }
    *reinterpret_cast<float2*>(out + (size_t)bn * HREAL + 2 * t) = r;
}

extern "C" void kernel_launch(void* const* d_in, const int* in_sizes, int n_in,
                              void* d_out, int out_size, void* d_ws, size_t ws_size,
                              hipStream_t stream) {
    const float* A1        = (const float*)d_in[0];
    const float* bond      = (const float*)d_in[1];
    const int*   ag        = (const int*)d_in[2];
    const int*   bg        = (const int*)d_in[3];
    const int*   maskn     = (const int*)d_in[6];
    const int*   maska     = (const int*)d_in[7];
    const float* W_fc1     = (const float*)d_in[8];
    const float* W_gc_nei  = (const float*)d_in[9];
    const float* b_gc_nei  = (const float*)d_in[10];
    const float* W_gc_atom = (const float*)d_in[11];
    const float* b_gc_atom = (const float*)d_in[12];
    const float* W_fc2a    = (const float*)d_in[13];
    const float* W_fc2b    = (const float*)d_in[14];
    const float* W_fc2     = (const float*)d_in[15];
    float* out = (float*)d_out;

    // ---- workspace carve-up ----
    char* p = (char*)d_ws;
    auto alloc = [&](size_t bytes) { char* r = p; p += (bytes + 63) & ~(size_t)63; return r; };
    __hip_bfloat16* A1b    = (__hip_bfloat16*)alloc((size_t)MA * 96 * 2);
    __hip_bfloat16* bondb  = (__hip_bfloat16*)alloc((size_t)MB * 32 * 2);
    __hip_bfloat16* af0    = (__hip_bfloat16*)alloc((size_t)MA * HP * 2);
    __hip_bfloat16* af1    = (__hip_bfloat16*)alloc((size_t)MA * HP * 2);
    __hip_bfloat16* Tb     = (__hip_bfloat16*)alloc((size_t)MA * HP * 2);
    __hip_bfloat16* neib   = (__hip_bfloat16*)alloc((size_t)MA * HP * 2);
    __hip_bfloat16* selfF  = (__hip_bfloat16*)alloc((size_t)MA * HP * 2);
    __hip_bfloat16* A2f    = (__hip_bfloat16*)alloc((size_t)MA * HP * 2);
    __hip_bfloat16* bondgc = (__hip_bfloat16*)alloc((size_t)MB * HP * 2);
    __hip_bfloat16* bnb    = (__hip_bfloat16*)alloc((size_t)MB * HP * 2);
    short8* pW1  = (short8*)alloc((size_t)NCT32 * 6  * 64 * 16);        // fc1          K=96
    short8* pWnei= (short8*)alloc((size_t)NCT32 * 20 * 64 * 16);        // gc_nei[:H]   K=320
    short8* pWga = (short8*)alloc((size_t)NCT32 * 40 * 64 * 16);        // gc_atom cat  K=640
    short8* pWbd = (short8*)alloc((size_t)2 * NCT32 * 2 * 64 * 16);     // bond dual    K=32, 20 ct
    short8* pWfd = (short8*)alloc((size_t)2 * NCT32 * 20 * 64 * 16);    // fc2 | fc2a   K=320, 20 ct

    // ---- prep: convs + packs in one launch ----
    Prep cfg;
    cfg.a1src = A1;   cfg.a1dst = A1b;
    cfg.bsrc  = bond; cfg.bdst  = bondb;
    //           W                                  dst                          Kreal  KT KTf off blk0
    cfg.j[0] = { W_fc1,                             pW1,                         AFDIM, 6,  6,  0,   0 };
    cfg.j[1] = { W_gc_nei,                          pWnei,                       HREAL, 20, 20, 0,  15 };
    cfg.j[2] = { W_gc_atom,                         pWga,                        HREAL, 20, 40, 0,  65 };
    cfg.j[3] = { W_gc_atom + (size_t)HREAL * HREAL, pWga,                        HREAL, 20, 40, 20, 115 };
    cfg.j[4] = { W_gc_nei + (size_t)HREAL * HREAL,  pWbd,                        BFDIM, 2,  2,  0, 165 };
    cfg.j[5] = { W_fc2b,                            pWbd + (size_t)NCT32*2*64,   BFDIM, 2,  2,  0, 170 };
    cfg.j[6] = { W_fc2,                             pWfd,                        HREAL, 20, 20, 0, 175 };
    cfg.j[7] = { W_fc2a,                            pWfd + (size_t)NCT32*20*64,  HREAL, 20, 20, 0, 225 };
    prep_all<<<dim3(PREP_BLKS), dim3(256), 0, stream>>>(cfg);

    const dim3 t256(256);

    // ---- input-layer GEMMs ----
    gemm64<6, 6, true><<<dim3(MA / 64, 1), t256, 0, stream>>>(
        A1b, A1b, pW1, nullptr, nullptr, af0, nullptr);
    gemm64<2, 2, false><<<dim3(MB / 64, 2), t256, 0, stream>>>(
        bondb, bondb, pWbd, b_gc_nei, nullptr, bondgc, bnb);

    // ---- graph-conv iterations ----
    const __hip_bfloat16* af = af0;
    __hip_bfloat16* afn = af1;
    for (int it = 0; it < 2; ++it) {
        gemm64<20, 20, false><<<dim3(MA / 64, 1), t256, 0, stream>>>(
            af, af, pWnei, nullptr, nullptr, Tb, nullptr);
        gather_relu_sum_bf<<<dim3(MA / 2), dim3(320), 0, stream>>>(
            (const u32*)Tb, (const u32*)bondgc, ag, bg, maskn, (u32*)neib);
        gemm64<40, 20, true><<<dim3(MA / 64, 1), t256, 0, stream>>>(
            af, neib, pWga, b_gc_atom, nullptr, afn, nullptr);
        const __hip_bfloat16* t = afn; afn = (__hip_bfloat16*)af; af = t;
    }

    // ---- final layer: selfF (ct<10) and A2f (ct>=10) in one dual GEMM ----
    gemm64<20, 20, false><<<dim3(MA / 64, 2), t256, 0, stream>>>(
        af, af, pWfd, nullptr, nullptr, selfF, A2f);
    final_bf<<<dim3(MA / 2), dim3(320), 0, stream>>>(
        (const u32*)A2f, (const u32*)bnb, (const u32*)selfF, ag, bg, maskn, maska, out);
}

// Round 4
// 157.343 us; speedup vs baseline: 3.2262x; 1.3772x over previous
//
#include <hip/hip_runtime.h>
#include <hip/hip_bf16.h>

// Problem constants
#define BATCH 64
#define NATOM 120
#define NNB 10
#define NBOND 250
#define AFDIM 82
#define BFDIM 6
#define HREAL 300
#define HP 320            // padded H (bf16 activation row stride); pad cols hold exact 0
#define NCT32 10          // 10 col-tiles of 32 -> 320
#define MA (BATCH*NATOM)  // 7680
#define MB (BATCH*NBOND)  // 16000

typedef short short8 __attribute__((ext_vector_type(8)));   // 8 bf16 (4 VGPRs)
typedef float f32x16 __attribute__((ext_vector_type(16)));  // 32x32 MFMA accumulator
typedef unsigned int u32;
typedef u32 u32x2 __attribute__((ext_vector_type(2)));
typedef unsigned short u16;

__device__ __forceinline__ float bflo(u32 v) { return __builtin_bit_cast(float, v << 16); }
__device__ __forceinline__ float bfhi(u32 v) { return __builtin_bit_cast(float, v & 0xffff0000u); }
__device__ __forceinline__ u16 f2bf(float f) {
    __hip_bfloat16 h = __float2bfloat16(f);
    return __builtin_bit_cast(u16, h);
}

// ================= prep: convs + weight packs + packed nbr table in ONE launch =================
struct PackJob { const float* W; short8* dst; int Kreal, KT, KTfull, ktOff, blk0; };
struct Prep {
    const float* a1src; __hip_bfloat16* a1dst;   // [MA][82] -> [MA][96]
    const float* bsrc;  __hip_bfloat16* bdst;    // [MB][6]  -> [MB][32]
    const int *mn, *agp, *bgp; u32* pk;          // packed nbr table [MA*NNB]
    PackJob j[8];
};

#define CONV1_BLKS 2880   // MA*96/256
#define CONV2_BLKS 2000   // MB*32/256
#define PACK_BASE  (CONV1_BLKS + CONV2_BLKS)
#define PACK_BLKS  275
#define PK_BASE    (PACK_BASE + PACK_BLKS)
#define PK_BLKS    300    // MA*NNB/256 = 76800/256
#define PREP_BLKS  (PK_BASE + PK_BLKS)   // 5455

__global__ __launch_bounds__(256) void prep_all(Prep cfg) {
    const int bid = blockIdx.x;
    const int tid = threadIdx.x;
    if (bid < CONV1_BLKS) {
        int id = bid * 256 + tid;                 // exact multiple
        int r = id / 96, c = id - r * 96;
        float f = (c < AFDIM) ? cfg.a1src[(size_t)r * AFDIM + c] : 0.f;
        cfg.a1dst[id] = __float2bfloat16(f);
    } else if (bid < PACK_BASE) {
        int id = (bid - CONV1_BLKS) * 256 + tid;  // exact multiple
        int r = id >> 5, c = id & 31;
        float f = (c < BFDIM) ? cfg.bsrc[(size_t)r * BFDIM + c] : 0.f;
        cfg.bdst[id] = __float2bfloat16(f);
    } else if (bid < PK_BASE) {
        const int pid = bid - PACK_BASE;
        int ji = 0;
#pragma unroll
        for (int i = 1; i < 8; ++i) if (pid >= cfg.j[i].blk0) ji = i;
        const PackJob J = cfg.j[ji];
        int id = (pid - J.blk0) * 256 + tid;
        int n = NCT32 * J.KT * 64;
        if (id >= n) return;
        int lane = id & 63;
        int kt = (id >> 6) % J.KT;
        int ct = id / (J.KT * 64);
        int col = ct * 32 + (lane & 31);
        int kbase = kt * 16 + (lane >> 5) * 8;
        short8 v;
#pragma unroll
        for (int jj = 0; jj < 8; ++jj) {
            int k = kbase + jj;
            float f = (k < J.Kreal && col < HREAL) ? J.W[(size_t)k * HREAL + col] : 0.f;
            v[jj] = (short)f2bf(f);
        }
        J.dst[(size_t)(ct * J.KTfull + J.ktOff + kt) * 64 + lane] = v;
    } else {
        int id = (bid - PK_BASE) * 256 + tid;     // exact multiple (76800)
        u32 w = 0;
        if (cfg.mn[id]) w = 0x80000000u | ((u32)cfg.agp[id] << 16) | (u32)cfg.bgp[id];
        cfg.pk[id] = w;
    }
}

// ================= MFMA GEMM device core (32x32x16) =================
// WAVES row-tiles of 32 per block, all waves share one ct-pair (W gets L1 reuse at WAVES=4).
// A-loads chunked (<=10 live fragments) to keep VGPR ~110 -> 4 waves/SIMD.
// A = [A1 | A2] split at kt==KT1. ct<NCT32 -> out0 bf16; else out1 bf16 or out1f fp32.
// Epilogue: +bias (bias0/bias1, nullptr->0), +addp (fp32, ADDF), relu (RELU).
template<int KT, int KT1, int WAVES, bool RELU, bool OUT1F, bool ADDF>
__device__ __forceinline__ void gemm_dev(
    int bx, int by, int tid,
    const __hip_bfloat16* __restrict__ A1,
    const __hip_bfloat16* __restrict__ A2,
    const short8* __restrict__ Wp,
    const float* __restrict__ bias0,
    const float* __restrict__ bias1,
    __hip_bfloat16* __restrict__ out0,
    __hip_bfloat16* __restrict__ out1,
    float* __restrict__ out1f,
    const float* __restrict__ addp) {
    const int lane = tid & 63;
    const int wv   = tid >> 6;                 // 0..WAVES-1
    const int m0   = bx * (32 * WAVES) + wv * 32;
    const int ct0  = by * 2;
    const int r1   = m0 + (lane & 31);
    const int koff = (lane >> 5) * 8;

    constexpr int S1  = KT1 * 16;
    constexpr int S2  = (KT - KT1) * 16;
    constexpr int CH  = (KT >= 10) ? 10 : KT;  // live A-fragment window
    constexpr int NCH = KT / CH;

    f32x16 acc[2];
#pragma unroll
    for (int r = 0; r < 16; ++r) { acc[0][r] = 0.f; acc[1][r] = 0.f; }

    const short8* w0 = Wp + ((size_t)ct0 * KT) * 64 + lane;
    const short8* w1 = w0 + (size_t)KT * 64;

#pragma unroll
    for (int ch = 0; ch < NCH; ++ch) {
        short8 a[CH];
#pragma unroll
        for (int kt = 0; kt < CH; ++kt) {
            const int g = ch * CH + kt;
            if (g < KT1)
                a[kt] = *reinterpret_cast<const short8*>(A1 + (size_t)r1 * S1 + g * 16 + koff);
            else
                a[kt] = *reinterpret_cast<const short8*>(A2 + (size_t)r1 * S2 + (g - KT1) * 16 + koff);
        }
#pragma unroll
        for (int kt = 0; kt < CH; ++kt) {
            const int g = ch * CH + kt;
            acc[0] = __builtin_amdgcn_mfma_f32_32x32x16_bf16(a[kt], w0[(size_t)g * 64], acc[0], 0, 0, 0);
            acc[1] = __builtin_amdgcn_mfma_f32_32x32x16_bf16(a[kt], w1[(size_t)g * 64], acc[1], 0, 0, 0);
        }
    }

#pragma unroll
    for (int c = 0; c < 2; ++c) {
        const int ct = ct0 + c;
        const bool second = (ct >= NCT32);
        const int colb = second ? ct * 32 - HP : ct * 32;
        const int col = colb + (lane & 31);
        __hip_bfloat16* op = second ? out1 : out0;
        const float* bp = second ? bias1 : bias0;
        const float bb = (bp && col < HREAL) ? bp[col] : 0.f;
#pragma unroll
        for (int r = 0; r < 16; ++r) {
            const int row = m0 + (r & 3) + 8 * (r >> 2) + 4 * (lane >> 5);
            float v = acc[c][r] + bb;
            if (ADDF) v += addp[(size_t)row * HP + col];
            if (RELU) v = fmaxf(v, 0.f);
            if (second) {
                if (OUT1F) out1f[(size_t)row * HP + col] = v;
                else       out1[(size_t)row * HP + col] = __float2bfloat16(v);
            } else {
                op[(size_t)row * HP + col] = __float2bfloat16(v);
            }
        }
    }
}

// ---- input GEMMs: fc1 (600 2-wave blocks) + bond dual (2500 2-wave blocks) in one launch ----
#define FC1_BLKS  (MA/64 * 5)          // 600
#define BOND_BLKS (MB/64 * 10)         // 2500
__global__ __launch_bounds__(128)
void k_input_gemms(const __hip_bfloat16* __restrict__ A1b,
                   const __hip_bfloat16* __restrict__ bondb,
                   const short8* __restrict__ pW1,
                   const short8* __restrict__ pWbd,
                   const float* __restrict__ bgn,
                   __hip_bfloat16* __restrict__ af0,
                   __hip_bfloat16* __restrict__ bondgc,
                   __hip_bfloat16* __restrict__ bnb) {
    const int bid = blockIdx.x;
    if (bid < FC1_BLKS) {
        gemm_dev<6, 6, 2, true, false, false>(bid % (MA/64), bid / (MA/64), threadIdx.x,
                                              A1b, A1b, pW1, nullptr, nullptr, af0, nullptr, nullptr, nullptr);
    } else {
        const int b2 = bid - FC1_BLKS;
        gemm_dev<2, 2, 2, false, false, false>(b2 % (MB/64), b2 / (MB/64), threadIdx.x,
                                               bondb, bondb, pWbd, bgn, nullptr, bondgc, bnb, nullptr, nullptr);
    }
}

// ---- per-iteration stage 1 (4-wave): Tb = af@W_nei  AND  U = af@W_gaTop + b_gc_atom (fp32) ----
__global__ __launch_bounds__(256)
void k_gemm_nu(const __hip_bfloat16* __restrict__ af, const short8* __restrict__ W,
               const float* __restrict__ bias1,
               __hip_bfloat16* __restrict__ Tb, float* __restrict__ U) {
    gemm_dev<20, 20, 4, false, true, false>(blockIdx.x, blockIdx.y, threadIdx.x,
                                            af, af, W, nullptr, bias1, Tb, nullptr, U, nullptr);
}

// ---- per-iteration stage 3 (2-wave): afn = relu(U + neib@W_gaBot) ----
__global__ __launch_bounds__(128)
void k_gemm_bot(const __hip_bfloat16* __restrict__ neib, const short8* __restrict__ W,
                const float* __restrict__ U, __hip_bfloat16* __restrict__ afn) {
    gemm_dev<20, 20, 2, true, false, true>(blockIdx.x, blockIdx.y, threadIdx.x,
                                           neib, neib, W, nullptr, nullptr, afn, nullptr, nullptr, U);
}

// ---- final dual GEMM (4-wave): selfF = af@W_fc2 (ct<10), A2f = af@W_fc2a (ct>=10) ----
__global__ __launch_bounds__(256)
void k_gemm_final(const __hip_bfloat16* __restrict__ af, const short8* __restrict__ W,
                  __hip_bfloat16* __restrict__ selfF, __hip_bfloat16* __restrict__ A2f) {
    gemm_dev<20, 20, 4, false, false, false>(blockIdx.x, blockIdx.y, threadIdx.x,
                                             af, af, W, nullptr, nullptr, selfF, A2f, nullptr, nullptr);
}

// ================= gather + relu + masked sum (4 rows/block, u32x2 lanes) =================
__global__ __launch_bounds__(320)
void gather2(const u32* __restrict__ T,       // [MA][160]
             const u32* __restrict__ BG,      // [MB][160]
             const u32* __restrict__ pk,      // packed mask|ag|bg
             u32* __restrict__ nei) {
    const int bn = blockIdx.x * 4 + threadIdx.x / 80;
    const int t2 = (threadIdx.x % 80) * 2;    // u32 offset within row
    const int b  = bn / NATOM;
    const int base = bn * NNB;
    float lo0 = 0.f, hi0 = 0.f, lo1 = 0.f, hi1 = 0.f;
#pragma unroll
    for (int j = 0; j < NNB; ++j) {
        const u32 w = pk[base + j];
        if ((int)w < 0) {
            const int a  = (w >> 16) & 0xff;
            const int bo = w & 0xffff;
            u32x2 ta = *reinterpret_cast<const u32x2*>(T  + (size_t)(b * NATOM + a)  * 160 + t2);
            u32x2 tb = *reinterpret_cast<const u32x2*>(BG + (size_t)(b * NBOND + bo) * 160 + t2);
            lo0 += fmaxf(bflo(ta[0]) + bflo(tb[0]), 0.f);
            hi0 += fmaxf(bfhi(ta[0]) + bfhi(tb[0]), 0.f);
            lo1 += fmaxf(bflo(ta[1]) + bflo(tb[1]), 0.f);
            hi1 += fmaxf(bfhi(ta[1]) + bfhi(tb[1]), 0.f);
        }
    }
    u32x2 o;
    o[0] = (u32)f2bf(lo0) | ((u32)f2bf(hi0) << 16);
    o[1] = (u32)f2bf(lo1) | ((u32)f2bf(hi1) << 16);
    *reinterpret_cast<u32x2*>(nei + (size_t)bn * 160 + t2) = o;
}

// ================= final: out = maska ? selfF * sum_j mask (A2f[ag]*bnb[bg]) : 0 =================
__global__ __launch_bounds__(320)
void final2(const u32* __restrict__ A2f,
            const u32* __restrict__ bnb,
            const u32* __restrict__ selfF,
            const u32* __restrict__ pk,
            const int* __restrict__ maska,
            float* __restrict__ out) {        // [MA][300] fp32
    const int bn = blockIdx.x * 4 + threadIdx.x / 80;
    const int tt = threadIdx.x % 80;
    if (tt >= 75) return;
    const int t2 = tt * 2;
    const int b  = bn / NATOM;
    const int base = bn * NNB;
    float lo0 = 0.f, hi0 = 0.f, lo1 = 0.f, hi1 = 0.f;
#pragma unroll
    for (int j = 0; j < NNB; ++j) {
        const u32 w = pk[base + j];
        if ((int)w < 0) {
            const int a  = (w >> 16) & 0xff;
            const int bo = w & 0xffff;
            u32x2 va = *reinterpret_cast<const u32x2*>(A2f + (size_t)(b * NATOM + a)  * 160 + t2);
            u32x2 vb = *reinterpret_cast<const u32x2*>(bnb + (size_t)(b * NBOND + bo) * 160 + t2);
            lo0 += bflo(va[0]) * bflo(vb[0]);
            hi0 += bfhi(va[0]) * bfhi(vb[0]);
            lo1 += bflo(va[1]) * bflo(vb[1]);
            hi1 += bfhi(va[1]) * bfhi(vb[1]);
        }
    }
    float4 r = make_float4(0.f, 0.f, 0.f, 0.f);
    if (maska[bn]) {
        u32x2 s = *reinterpret_cast<const u32x2*>(selfF + (size_t)bn * 160 + t2);
        r.x = bflo(s[0]) * lo0;
        r.y = bfhi(s[0]) * hi0;
        r.z = bflo(s[1]) * lo1;
        r.w = bfhi(s[1]) * hi1;
    }
    *reinterpret_cast<float4*>(out + (size_t)bn * HREAL + tt * 4) = r;
}

extern "C" void kernel_launch(void* const* d_in, const int* in_sizes, int n_in,
                              void* d_out, int out_size, void* d_ws, size_t ws_size,
                              hipStream_t stream) {
    const float* A1        = (const float*)d_in[0];
    const float* bond      = (const float*)d_in[1];
    const int*   ag        = (const int*)d_in[2];
    const int*   bg        = (const int*)d_in[3];
    const int*   maskn     = (const int*)d_in[6];
    const int*   maska     = (const int*)d_in[7];
    const float* W_fc1     = (const float*)d_in[8];
    const float* W_gc_nei  = (const float*)d_in[9];
    const float* b_gc_nei  = (const float*)d_in[10];
    const float* W_gc_atom = (const float*)d_in[11];
    const float* b_gc_atom = (const float*)d_in[12];
    const float* W_fc2a    = (const float*)d_in[13];
    const float* W_fc2b    = (const float*)d_in[14];
    const float* W_fc2     = (const float*)d_in[15];
    float* out = (float*)d_out;

    // ---- workspace carve-up ----
    char* p = (char*)d_ws;
    auto alloc = [&](size_t bytes) { char* r = p; p += (bytes + 63) & ~(size_t)63; return r; };
    __hip_bfloat16* A1b    = (__hip_bfloat16*)alloc((size_t)MA * 96 * 2);
    __hip_bfloat16* bondb  = (__hip_bfloat16*)alloc((size_t)MB * 32 * 2);
    __hip_bfloat16* af0    = (__hip_bfloat16*)alloc((size_t)MA * HP * 2);
    __hip_bfloat16* af1    = (__hip_bfloat16*)alloc((size_t)MA * HP * 2);
    __hip_bfloat16* Tb     = (__hip_bfloat16*)alloc((size_t)MA * HP * 2);
    __hip_bfloat16* neib   = (__hip_bfloat16*)alloc((size_t)MA * HP * 2);
    __hip_bfloat16* selfF  = (__hip_bfloat16*)alloc((size_t)MA * HP * 2);
    __hip_bfloat16* A2f    = (__hip_bfloat16*)alloc((size_t)MA * HP * 2);
    __hip_bfloat16* bondgc = (__hip_bfloat16*)alloc((size_t)MB * HP * 2);
    __hip_bfloat16* bnb    = (__hip_bfloat16*)alloc((size_t)MB * HP * 2);
    float*          U      = (float*)alloc((size_t)MA * HP * 4);        // fp32 af@W_gaTop + bias
    u32*            pk     = (u32*)alloc((size_t)MA * NNB * 4);         // packed nbr table
    short8* pW1  = (short8*)alloc((size_t)NCT32 * 6  * 64 * 16);        // fc1          K=96
    short8* pWnei= (short8*)alloc((size_t)2 * NCT32 * 20 * 64 * 16);    // nei | gaTop  K=320, 20 ct
    short8* pWgb = (short8*)alloc((size_t)NCT32 * 20 * 64 * 16);        // gaBot        K=320
    short8* pWbd = (short8*)alloc((size_t)2 * NCT32 * 2 * 64 * 16);     // bond dual    K=32, 20 ct
    short8* pWfd = (short8*)alloc((size_t)2 * NCT32 * 20 * 64 * 16);    // fc2 | fc2a   K=320, 20 ct

    // ---- prep: convs + packs + pk in one launch ----
    Prep cfg;
    cfg.a1src = A1;   cfg.a1dst = A1b;
    cfg.bsrc  = bond; cfg.bdst  = bondb;
    cfg.mn = maskn; cfg.agp = ag; cfg.bgp = bg; cfg.pk = pk;
    //           W                                  dst                          Kreal  KT KTf off blk0
    cfg.j[0] = { W_fc1,                             pW1,                         AFDIM, 6,  6,  0,   0 };
    cfg.j[1] = { W_gc_nei,                          pWnei,                       HREAL, 20, 20, 0,  15 };
    cfg.j[2] = { W_gc_atom,                         pWnei + (size_t)NCT32*20*64, HREAL, 20, 20, 0,  65 };
    cfg.j[3] = { W_gc_atom + (size_t)HREAL * HREAL, pWgb,                        HREAL, 20, 20, 0, 115 };
    cfg.j[4] = { W_gc_nei + (size_t)HREAL * HREAL,  pWbd,                        BFDIM, 2,  2,  0, 165 };
    cfg.j[5] = { W_fc2b,                            pWbd + (size_t)NCT32*2*64,   BFDIM, 2,  2,  0, 170 };
    cfg.j[6] = { W_fc2,                             pWfd,                        HREAL, 20, 20, 0, 175 };
    cfg.j[7] = { W_fc2a,                            pWfd + (size_t)NCT32*20*64,  HREAL, 20, 20, 0, 225 };
    prep_all<<<dim3(PREP_BLKS), dim3(256), 0, stream>>>(cfg);

    // ---- input GEMMs (fc1 + bond dual), 2-wave blocks ----
    k_input_gemms<<<dim3(FC1_BLKS + BOND_BLKS), dim3(128), 0, stream>>>(
        A1b, bondb, pW1, pWbd, b_gc_nei, af0, bondgc, bnb);

    const dim3 gNU(MA / 128, 10);   // (60,10) 4-wave dual: Tb + U
    const dim3 gBOT(MA / 64, 5);    // (120,5) 2-wave
    const dim3 t256(256), t128(128);

    // ---- graph-conv iterations ----
    const __hip_bfloat16* af = af0;
    __hip_bfloat16* afn = af1;
    for (int it = 0; it < 2; ++it) {
        k_gemm_nu<<<gNU, t256, 0, stream>>>(af, pWnei, b_gc_atom, Tb, U);
        gather2<<<dim3(MA / 4), dim3(320), 0, stream>>>(
            (const u32*)Tb, (const u32*)bondgc, pk, (u32*)neib);
        k_gemm_bot<<<gBOT, t128, 0, stream>>>(neib, pWgb, U, afn);
        const __hip_bfloat16* t = afn; afn = (__hip_bfloat16*)af; af = t;
    }

    // ---- final layer ----
    k_gemm_final<<<gNU, t256, 0, stream>>>(af, pWfd, selfF, A2f);
    final2<<<dim3(MA / 4), dim3(320), 0, stream>>>(
        (const u32*)A2f, (const u32*)bnb, (const u32*)selfF, pk, maska, out);
}

// Round 5
// 142.789 us; speedup vs baseline: 3.5551x; 1.1019x over previous
//
#include <hip/hip_runtime.h>
#include <hip/hip_bf16.h>

// Problem constants
#define BATCH 64
#define NATOM 120
#define NNB 10
#define NBOND 250
#define AFDIM 82
#define BFDIM 6
#define HREAL 300
#define HP 320            // padded H (bf16 activation row stride); pad cols hold exact 0
#define NCT32 10          // 10 col-tiles of 32 -> 320
#define MA (BATCH*NATOM)  // 7680
#define MB (BATCH*NBOND)  // 16000

typedef short short8 __attribute__((ext_vector_type(8)));   // 8 bf16 (4 VGPRs)
typedef float f32x16 __attribute__((ext_vector_type(16)));  // 32x32 MFMA accumulator
typedef unsigned int u32;
typedef u32 u32x2 __attribute__((ext_vector_type(2)));
typedef unsigned short u16;

__device__ __forceinline__ float bflo(u32 v) { return __builtin_bit_cast(float, v << 16); }
__device__ __forceinline__ float bfhi(u32 v) { return __builtin_bit_cast(float, v & 0xffff0000u); }
__device__ __forceinline__ u16 f2bf(float f) {
    __hip_bfloat16 h = __float2bfloat16(f);
    return __builtin_bit_cast(u16, h);
}

// ================= prep: convs + weight packs + packed nbr table in ONE launch =================
struct PackJob { const float* W; short8* dst; int Kreal, KT, KTfull, ktOff, blk0; };
struct Prep {
    const float* a1src; __hip_bfloat16* a1dst;   // [MA][82] -> [MA][96]
    const float* bsrc;  __hip_bfloat16* bdst;    // [MB][6]  -> [MB][32]
    const int *mn, *agp, *bgp; u32* pk;          // packed nbr table [MA*NNB]
    PackJob j[8];
};

#define CONV1_BLKS 2880   // MA*96/256
#define CONV2_BLKS 2000   // MB*32/256
#define PACK_BASE  (CONV1_BLKS + CONV2_BLKS)
#define PACK_BLKS  275
#define PK_BASE    (PACK_BASE + PACK_BLKS)
#define PK_BLKS    300    // MA*NNB/256 = 76800/256
#define PREP_BLKS  (PK_BASE + PK_BLKS)   // 5455

__global__ __launch_bounds__(256) void prep_all(Prep cfg) {
    const int bid = blockIdx.x;
    const int tid = threadIdx.x;
    if (bid < CONV1_BLKS) {
        int id = bid * 256 + tid;                 // exact multiple
        int r = id / 96, c = id - r * 96;
        float f = (c < AFDIM) ? cfg.a1src[(size_t)r * AFDIM + c] : 0.f;
        cfg.a1dst[id] = __float2bfloat16(f);
    } else if (bid < PACK_BASE) {
        int id = (bid - CONV1_BLKS) * 256 + tid;  // exact multiple
        int r = id >> 5, c = id & 31;
        float f = (c < BFDIM) ? cfg.bsrc[(size_t)r * BFDIM + c] : 0.f;
        cfg.bdst[id] = __float2bfloat16(f);
    } else if (bid < PK_BASE) {
        const int pid = bid - PACK_BASE;
        int ji = 0;
#pragma unroll
        for (int i = 1; i < 8; ++i) if (pid >= cfg.j[i].blk0) ji = i;
        const PackJob J = cfg.j[ji];
        int id = (pid - J.blk0) * 256 + tid;
        int n = NCT32 * J.KT * 64;
        if (id >= n) return;
        int lane = id & 63;
        int kt = (id >> 6) % J.KT;
        int ct = id / (J.KT * 64);
        int col = ct * 32 + (lane & 31);
        int kbase = kt * 16 + (lane >> 5) * 8;
        short8 v;
#pragma unroll
        for (int jj = 0; jj < 8; ++jj) {
            int k = kbase + jj;
            float f = (k < J.Kreal && col < HREAL) ? J.W[(size_t)k * HREAL + col] : 0.f;
            v[jj] = (short)f2bf(f);
        }
        J.dst[(size_t)(ct * J.KTfull + J.ktOff + kt) * 64 + lane] = v;
    } else {
        int id = (bid - PK_BASE) * 256 + tid;     // exact multiple (76800)
        u32 w = 0;
        if (cfg.mn[id]) w = 0x80000000u | ((u32)cfg.agp[id] << 16) | (u32)cfg.bgp[id];
        cfg.pk[id] = w;
    }
}

// ================= MFMA GEMM device core (32x32x16) =================
// WAVES row-tiles of 32 per block, all waves share one ct-pair (W gets L1 reuse at WAVES=4).
// A-loads chunked (<=10 live fragments) to keep VGPR ~110.
// A = [A1 | A2] split at kt==KT1. ct<NCT32 -> out0 bf16; else out1 bf16 or out1f fp32.
// Epilogue: +bias (bias0/bias1, nullptr->0), +addp (fp32, ADDF), relu (RELU).
template<int KT, int KT1, int WAVES, bool RELU, bool OUT1F, bool ADDF>
__device__ __forceinline__ void gemm_dev(
    int bx, int by, int tid,
    const __hip_bfloat16* __restrict__ A1,
    const __hip_bfloat16* __restrict__ A2,
    const short8* __restrict__ Wp,
    const float* __restrict__ bias0,
    const float* __restrict__ bias1,
    __hip_bfloat16* __restrict__ out0,
    __hip_bfloat16* __restrict__ out1,
    float* __restrict__ out1f,
    const float* __restrict__ addp) {
    const int lane = tid & 63;
    const int wv   = tid >> 6;                 // 0..WAVES-1
    const int m0   = bx * (32 * WAVES) + wv * 32;
    const int ct0  = by * 2;
    const int r1   = m0 + (lane & 31);
    const int koff = (lane >> 5) * 8;

    constexpr int S1  = KT1 * 16;
    constexpr int S2  = (KT - KT1) * 16;
    constexpr int CH  = (KT >= 10) ? 10 : KT;  // live A-fragment window
    constexpr int NCH = KT / CH;

    f32x16 acc[2];
#pragma unroll
    for (int r = 0; r < 16; ++r) { acc[0][r] = 0.f; acc[1][r] = 0.f; }

    const short8* w0 = Wp + ((size_t)ct0 * KT) * 64 + lane;
    const short8* w1 = w0 + (size_t)KT * 64;

#pragma unroll
    for (int ch = 0; ch < NCH; ++ch) {
        short8 a[CH];
#pragma unroll
        for (int kt = 0; kt < CH; ++kt) {
            const int g = ch * CH + kt;
            if (g < KT1)
                a[kt] = *reinterpret_cast<const short8*>(A1 + (size_t)r1 * S1 + g * 16 + koff);
            else
                a[kt] = *reinterpret_cast<const short8*>(A2 + (size_t)r1 * S2 + (g - KT1) * 16 + koff);
        }
#pragma unroll
        for (int kt = 0; kt < CH; ++kt) {
            const int g = ch * CH + kt;
            acc[0] = __builtin_amdgcn_mfma_f32_32x32x16_bf16(a[kt], w0[(size_t)g * 64], acc[0], 0, 0, 0);
            acc[1] = __builtin_amdgcn_mfma_f32_32x32x16_bf16(a[kt], w1[(size_t)g * 64], acc[1], 0, 0, 0);
        }
    }

#pragma unroll
    for (int c = 0; c < 2; ++c) {
        const int ct = ct0 + c;
        const bool second = (ct >= NCT32);
        const int colb = second ? ct * 32 - HP : ct * 32;
        const int col = colb + (lane & 31);
        __hip_bfloat16* op = second ? out1 : out0;
        const float* bp = second ? bias1 : bias0;
        const float bb = (bp && col < HREAL) ? bp[col] : 0.f;
#pragma unroll
        for (int r = 0; r < 16; ++r) {
            const int row = m0 + (r & 3) + 8 * (r >> 2) + 4 * (lane >> 5);
            float v = acc[c][r] + bb;
            if (ADDF) v += addp[(size_t)row * HP + col];
            if (RELU) v = fmaxf(v, 0.f);
            if (second) {
                if (OUT1F) out1f[(size_t)row * HP + col] = v;
                else       out1[(size_t)row * HP + col] = __float2bfloat16(v);
            } else {
                op[(size_t)row * HP + col] = __float2bfloat16(v);
            }
        }
    }
}

// ---- input GEMMs: fc1 (600 2-wave blocks) + bond dual (2500 2-wave blocks) in one launch ----
#define FC1_BLKS  (MA/64 * 5)          // 600
#define BOND_BLKS (MB/64 * 10)         // 2500
__global__ __launch_bounds__(128)
void k_input_gemms(const __hip_bfloat16* __restrict__ A1b,
                   const __hip_bfloat16* __restrict__ bondb,
                   const short8* __restrict__ pW1,
                   const short8* __restrict__ pWbd,
                   const float* __restrict__ bgn,
                   __hip_bfloat16* __restrict__ af0,
                   __hip_bfloat16* __restrict__ bondgc,
                   __hip_bfloat16* __restrict__ bnb) {
    const int bid = blockIdx.x;
    if (bid < FC1_BLKS) {
        gemm_dev<6, 6, 2, true, false, false>(bid % (MA/64), bid / (MA/64), threadIdx.x,
                                              A1b, A1b, pW1, nullptr, nullptr, af0, nullptr, nullptr, nullptr);
    } else {
        const int b2 = bid - FC1_BLKS;
        gemm_dev<2, 2, 2, false, false, false>(b2 % (MB/64), b2 / (MB/64), threadIdx.x,
                                               bondb, bondb, pWbd, bgn, nullptr, bondgc, bnb, nullptr, nullptr);
    }
}

// ---- per-iteration stage 1 (4-wave): Tb = af@W_nei  AND  U = af@W_gaTop + b_gc_atom (fp32) ----
__global__ __launch_bounds__(256)
void k_gemm_nu(const __hip_bfloat16* __restrict__ af, const short8* __restrict__ W,
               const float* __restrict__ bias1,
               __hip_bfloat16* __restrict__ Tb, float* __restrict__ U) {
    gemm_dev<20, 20, 4, false, true, false>(blockIdx.x, blockIdx.y, threadIdx.x,
                                            af, af, W, nullptr, bias1, Tb, nullptr, U, nullptr);
}

// ---- per-iteration stage 3 (2-wave): afn = relu(U + neib@W_gaBot) ----
__global__ __launch_bounds__(128)
void k_gemm_bot(const __hip_bfloat16* __restrict__ neib, const short8* __restrict__ W,
                const float* __restrict__ U, __hip_bfloat16* __restrict__ afn) {
    gemm_dev<20, 20, 2, true, false, true>(blockIdx.x, blockIdx.y, threadIdx.x,
                                           neib, neib, W, nullptr, nullptr, afn, nullptr, nullptr, U);
}

// ---- final dual GEMM (4-wave): selfF = af@W_fc2 (ct<10), A2f = af@W_fc2a (ct>=10) ----
__global__ __launch_bounds__(256)
void k_gemm_final(const __hip_bfloat16* __restrict__ af, const short8* __restrict__ W,
                  __hip_bfloat16* __restrict__ selfF, __hip_bfloat16* __restrict__ A2f) {
    gemm_dev<20, 20, 4, false, false, false>(blockIdx.x, blockIdx.y, threadIdx.x,
                                             af, af, W, nullptr, nullptr, selfF, A2f, nullptr, nullptr);
}

// ================= batch-LDS gather: nei = sum_j relu(T[ag] + bondgc[bg]) =================
// One block per (batch, col-eighth). Stage T[b,:,c0:c0+40u32] (9.6KB) + bondgc[b,:,same] (20KB)
// + pk (4.8KB) into LDS; all neighbor reads then hit LDS instead of scattered L2/L3.
// LDS = (120*20 + 250*20 + 1200)*4 = 34400 B -> 2+ blocks/CU co-resident (stage/compute overlap).
#define GBLK (BATCH * 8)   // 512 blocks
__global__ __launch_bounds__(512)
void gather_lds(const u32* __restrict__ T,       // [MA][160]
                const u32* __restrict__ BG,      // [MB][160]
                const u32* __restrict__ pk,
                u32* __restrict__ nei) {
    extern __shared__ u32 sm[];
    u32* TL = sm;                 // [120][20]
    u32* BL = sm + 120 * 20;      // [250][20]
    u32* PL = BL + 250 * 20;      // [1200]
    const int b   = blockIdx.x >> 3;
    const int c0  = (blockIdx.x & 7) * 20;     // u32 col base within HP/2=160
    const int tid = threadIdx.x;

    for (int i = tid; i < 120 * 10; i += 512) {
        int r = i / 10, p = i - r * 10;
        *reinterpret_cast<u32x2*>(&TL[r * 20 + 2 * p]) =
            *reinterpret_cast<const u32x2*>(T + (size_t)(b * NATOM + r) * (HP / 2) + c0 + 2 * p);
    }
    for (int i = tid; i < 250 * 10; i += 512) {
        int r = i / 10, p = i - r * 10;
        *reinterpret_cast<u32x2*>(&BL[r * 20 + 2 * p]) =
            *reinterpret_cast<const u32x2*>(BG + (size_t)(b * NBOND + r) * (HP / 2) + c0 + 2 * p);
    }
    for (int i = tid; i < NATOM * NNB; i += 512) PL[i] = pk[b * NATOM * NNB + i];
    __syncthreads();

    for (int i = tid; i < 120 * 10; i += 512) {
        const int row = i / 10, p = i - row * 10;
        float lo0 = 0.f, hi0 = 0.f, lo1 = 0.f, hi1 = 0.f;
#pragma unroll
        for (int j = 0; j < NNB; ++j) {
            const u32 w = PL[row * NNB + j];
            if ((int)w < 0) {
                const int a  = (w >> 16) & 0xff;
                const int bo = w & 0xffff;
                u32x2 ta = *reinterpret_cast<const u32x2*>(&TL[a * 20 + 2 * p]);
                u32x2 tb = *reinterpret_cast<const u32x2*>(&BL[bo * 20 + 2 * p]);
                lo0 += fmaxf(bflo(ta[0]) + bflo(tb[0]), 0.f);
                hi0 += fmaxf(bfhi(ta[0]) + bfhi(tb[0]), 0.f);
                lo1 += fmaxf(bflo(ta[1]) + bflo(tb[1]), 0.f);
                hi1 += fmaxf(bfhi(ta[1]) + bfhi(tb[1]), 0.f);
            }
        }
        u32x2 o;
        o[0] = (u32)f2bf(lo0) | ((u32)f2bf(hi0) << 16);
        o[1] = (u32)f2bf(lo1) | ((u32)f2bf(hi1) << 16);
        *reinterpret_cast<u32x2*>(nei + (size_t)(b * NATOM + row) * (HP / 2) + c0 + 2 * p) = o;
    }
}
#define GATHER_LDS_BYTES ((120*20 + 250*20 + 1200) * 4)   // 34400

// ================= batch-LDS final: out = maska ? selfF * sum_j mask (A2f[ag]*bnb[bg]) : 0 =================
__global__ __launch_bounds__(512)
void final_lds(const u32* __restrict__ A2f,      // [MA][160]
               const u32* __restrict__ bnb,      // [MB][160]
               const u32* __restrict__ selfF,    // [MA][160]
               const u32* __restrict__ pk,
               const int* __restrict__ maska,
               float* __restrict__ out) {        // [MA][300] fp32
    extern __shared__ u32 sm[];
    u32* AL = sm;                 // [120][20]
    u32* BL = sm + 120 * 20;      // [250][20]
    u32* PL = BL + 250 * 20;      // [1200]
    u32* ML = PL + 1200;          // [120]
    const int b   = blockIdx.x >> 3;
    const int c0  = (blockIdx.x & 7) * 20;
    const int tid = threadIdx.x;

    for (int i = tid; i < 120 * 10; i += 512) {
        int r = i / 10, p = i - r * 10;
        *reinterpret_cast<u32x2*>(&AL[r * 20 + 2 * p]) =
            *reinterpret_cast<const u32x2*>(A2f + (size_t)(b * NATOM + r) * (HP / 2) + c0 + 2 * p);
    }
    for (int i = tid; i < 250 * 10; i += 512) {
        int r = i / 10, p = i - r * 10;
        *reinterpret_cast<u32x2*>(&BL[r * 20 + 2 * p]) =
            *reinterpret_cast<const u32x2*>(bnb + (size_t)(b * NBOND + r) * (HP / 2) + c0 + 2 * p);
    }
    for (int i = tid; i < NATOM * NNB; i += 512) PL[i] = pk[b * NATOM * NNB + i];
    for (int i = tid; i < NATOM; i += 512) ML[i] = (u32)(maska[b * NATOM + i] != 0);
    __syncthreads();

    for (int i = tid; i < 120 * 10; i += 512) {
        const int row = i / 10, p = i - row * 10;
        const int cA = c0 + 2 * p;               // global u32 col; valid out iff cA < 150
        if (cA >= 150) continue;
        float lo0 = 0.f, hi0 = 0.f, lo1 = 0.f, hi1 = 0.f;
#pragma unroll
        for (int j = 0; j < NNB; ++j) {
            const u32 w = PL[row * NNB + j];
            if ((int)w < 0) {
                const int a  = (w >> 16) & 0xff;
                const int bo = w & 0xffff;
                u32x2 va = *reinterpret_cast<const u32x2*>(&AL[a * 20 + 2 * p]);
                u32x2 vb = *reinterpret_cast<const u32x2*>(&BL[bo * 20 + 2 * p]);
                lo0 += bflo(va[0]) * bflo(vb[0]);
                hi0 += bfhi(va[0]) * bfhi(vb[0]);
                lo1 += bflo(va[1]) * bflo(vb[1]);
                hi1 += bfhi(va[1]) * bfhi(vb[1]);
            }
        }
        float4 r4 = make_float4(0.f, 0.f, 0.f, 0.f);
        if (ML[row]) {
            u32x2 s = *reinterpret_cast<const u32x2*>(selfF + (size_t)(b * NATOM + row) * (HP / 2) + cA);
            r4.x = bflo(s[0]) * lo0;
            r4.y = bfhi(s[0]) * hi0;
            r4.z = bflo(s[1]) * lo1;
            r4.w = bfhi(s[1]) * hi1;
        }
        *reinterpret_cast<float4*>(out + (size_t)(b * NATOM + row) * HREAL + 2 * cA) = r4;
    }
}
#define FINAL_LDS_BYTES ((120*20 + 250*20 + 1200 + 120) * 4)   // 34880

extern "C" void kernel_launch(void* const* d_in, const int* in_sizes, int n_in,
                              void* d_out, int out_size, void* d_ws, size_t ws_size,
                              hipStream_t stream) {
    const float* A1        = (const float*)d_in[0];
    const float* bond      = (const float*)d_in[1];
    const int*   ag        = (const int*)d_in[2];
    const int*   bg        = (const int*)d_in[3];
    const int*   maskn     = (const int*)d_in[6];
    const int*   maska     = (const int*)d_in[7];
    const float* W_fc1     = (const float*)d_in[8];
    const float* W_gc_nei  = (const float*)d_in[9];
    const float* b_gc_nei  = (const float*)d_in[10];
    const float* W_gc_atom = (const float*)d_in[11];
    const float* b_gc_atom = (const float*)d_in[12];
    const float* W_fc2a    = (const float*)d_in[13];
    const float* W_fc2b    = (const float*)d_in[14];
    const float* W_fc2     = (const float*)d_in[15];
    float* out = (float*)d_out;

    // ---- workspace carve-up ----
    char* p = (char*)d_ws;
    auto alloc = [&](size_t bytes) { char* r = p; p += (bytes + 63) & ~(size_t)63; return r; };
    __hip_bfloat16* A1b    = (__hip_bfloat16*)alloc((size_t)MA * 96 * 2);
    __hip_bfloat16* bondb  = (__hip_bfloat16*)alloc((size_t)MB * 32 * 2);
    __hip_bfloat16* af0    = (__hip_bfloat16*)alloc((size_t)MA * HP * 2);
    __hip_bfloat16* af1    = (__hip_bfloat16*)alloc((size_t)MA * HP * 2);
    __hip_bfloat16* Tb     = (__hip_bfloat16*)alloc((size_t)MA * HP * 2);
    __hip_bfloat16* neib   = (__hip_bfloat16*)alloc((size_t)MA * HP * 2);
    __hip_bfloat16* selfF  = (__hip_bfloat16*)alloc((size_t)MA * HP * 2);
    __hip_bfloat16* A2f    = (__hip_bfloat16*)alloc((size_t)MA * HP * 2);
    __hip_bfloat16* bondgc = (__hip_bfloat16*)alloc((size_t)MB * HP * 2);
    __hip_bfloat16* bnb    = (__hip_bfloat16*)alloc((size_t)MB * HP * 2);
    float*          U      = (float*)alloc((size_t)MA * HP * 4);        // fp32 af@W_gaTop + bias
    u32*            pk     = (u32*)alloc((size_t)MA * NNB * 4);         // packed nbr table
    short8* pW1  = (short8*)alloc((size_t)NCT32 * 6  * 64 * 16);        // fc1          K=96
    short8* pWnei= (short8*)alloc((size_t)2 * NCT32 * 20 * 64 * 16);    // nei | gaTop  K=320, 20 ct
    short8* pWgb = (short8*)alloc((size_t)NCT32 * 20 * 64 * 16);        // gaBot        K=320
    short8* pWbd = (short8*)alloc((size_t)2 * NCT32 * 2 * 64 * 16);     // bond dual    K=32, 20 ct
    short8* pWfd = (short8*)alloc((size_t)2 * NCT32 * 20 * 64 * 16);    // fc2 | fc2a   K=320, 20 ct

    // ---- prep: convs + packs + pk in one launch ----
    Prep cfg;
    cfg.a1src = A1;   cfg.a1dst = A1b;
    cfg.bsrc  = bond; cfg.bdst  = bondb;
    cfg.mn = maskn; cfg.agp = ag; cfg.bgp = bg; cfg.pk = pk;
    //           W                                  dst                          Kreal  KT KTf off blk0
    cfg.j[0] = { W_fc1,                             pW1,                         AFDIM, 6,  6,  0,   0 };
    cfg.j[1] = { W_gc_nei,                          pWnei,                       HREAL, 20, 20, 0,  15 };
    cfg.j[2] = { W_gc_atom,                         pWnei + (size_t)NCT32*20*64, HREAL, 20, 20, 0,  65 };
    cfg.j[3] = { W_gc_atom + (size_t)HREAL * HREAL, pWgb,                        HREAL, 20, 20, 0, 115 };
    cfg.j[4] = { W_gc_nei + (size_t)HREAL * HREAL,  pWbd,                        BFDIM, 2,  2,  0, 165 };
    cfg.j[5] = { W_fc2b,                            pWbd + (size_t)NCT32*2*64,   BFDIM, 2,  2,  0, 170 };
    cfg.j[6] = { W_fc2,                             pWfd,                        HREAL, 20, 20, 0, 175 };
    cfg.j[7] = { W_fc2a,                            pWfd + (size_t)NCT32*20*64,  HREAL, 20, 20, 0, 225 };
    prep_all<<<dim3(PREP_BLKS), dim3(256), 0, stream>>>(cfg);

    // ---- input GEMMs (fc1 + bond dual), 2-wave blocks ----
    k_input_gemms<<<dim3(FC1_BLKS + BOND_BLKS), dim3(128), 0, stream>>>(
        A1b, bondb, pW1, pWbd, b_gc_nei, af0, bondgc, bnb);

    const dim3 gNU(MA / 128, 10);   // (60,10) 4-wave dual: Tb + U
    const dim3 gBOT(MA / 64, 5);    // (120,5) 2-wave
    const dim3 t256(256), t128(128), t512(512);

    // ---- graph-conv iterations ----
    const __hip_bfloat16* af = af0;
    __hip_bfloat16* afn = af1;
    for (int it = 0; it < 2; ++it) {
        k_gemm_nu<<<gNU, t256, 0, stream>>>(af, pWnei, b_gc_atom, Tb, U);
        gather_lds<<<dim3(GBLK), t512, GATHER_LDS_BYTES, stream>>>(
            (const u32*)Tb, (const u32*)bondgc, pk, (u32*)neib);
        k_gemm_bot<<<gBOT, t128, 0, stream>>>(neib, pWgb, U, afn);
        const __hip_bfloat16* t = afn; afn = (__hip_bfloat16*)af; af = t;
    }

    // ---- final layer ----
    k_gemm_final<<<gNU, t256, 0, stream>>>(af, pWfd, selfF, A2f);
    final_lds<<<dim3(GBLK), t512, FINAL_LDS_BYTES, stream>>>(
        (const u32*)A2f, (const u32*)bnb, (const u32*)selfF, pk, maska, out);
}

// Round 6
// 134.628 us; speedup vs baseline: 3.7705x; 1.0606x over previous
//
#include <hip/hip_runtime.h>
#include <hip/hip_bf16.h>

// Problem constants
#define BATCH 64
#define NATOM 120
#define NNB 10
#define NBOND 250
#define AFDIM 82
#define BFDIM 6
#define HREAL 300
#define HP 320            // padded H (bf16 activation row stride); pad cols hold exact 0
#define NCT32 10          // 10 col-tiles of 32 -> 320
#define MA (BATCH*NATOM)  // 7680
#define MB (BATCH*NBOND)  // 16000

typedef short short8 __attribute__((ext_vector_type(8)));   // 8 bf16 (4 VGPRs)
typedef float f32x16 __attribute__((ext_vector_type(16)));  // 32x32 MFMA accumulator
typedef unsigned int u32;
typedef u32 u32x2 __attribute__((ext_vector_type(2)));
typedef unsigned short u16;

__device__ __forceinline__ float bflo(u32 v) { return __builtin_bit_cast(float, v << 16); }
__device__ __forceinline__ float bfhi(u32 v) { return __builtin_bit_cast(float, v & 0xffff0000u); }
__device__ __forceinline__ u16 f2bf(float f) {
    __hip_bfloat16 h = __float2bfloat16(f);
    return __builtin_bit_cast(u16, h);
}

// ================= prep: convs + weight packs + packed nbr table in ONE launch =================
struct PackJob { const float* W; short8* dst; int Kreal, KT, KTfull, ktOff, blk0; };
struct Prep {
    const float* a1src; __hip_bfloat16* a1dst;   // [MA][82] -> [MA][96]
    const float* bsrc;  __hip_bfloat16* bdst;    // [MB][6]  -> [MB][32]
    const int *mn, *agp, *bgp; u32* pk;          // packed nbr table [MA*NNB]
    PackJob j[8];
};

#define CONV1_BLKS 2880   // MA*96/256
#define CONV2_BLKS 2000   // MB*32/256
#define PACK_BASE  (CONV1_BLKS + CONV2_BLKS)
#define PACK_BLKS  275
#define PK_BASE    (PACK_BASE + PACK_BLKS)
#define PK_BLKS    300    // MA*NNB/256 = 76800/256
#define PREP_BLKS  (PK_BASE + PK_BLKS)   // 5455

__global__ __launch_bounds__(256) void prep_all(Prep cfg) {
    const int bid = blockIdx.x;
    const int tid = threadIdx.x;
    if (bid < CONV1_BLKS) {
        int id = bid * 256 + tid;                 // exact multiple
        int r = id / 96, c = id - r * 96;
        float f = (c < AFDIM) ? cfg.a1src[(size_t)r * AFDIM + c] : 0.f;
        cfg.a1dst[id] = __float2bfloat16(f);
    } else if (bid < PACK_BASE) {
        int id = (bid - CONV1_BLKS) * 256 + tid;  // exact multiple
        int r = id >> 5, c = id & 31;
        float f = (c < BFDIM) ? cfg.bsrc[(size_t)r * BFDIM + c] : 0.f;
        cfg.bdst[id] = __float2bfloat16(f);
    } else if (bid < PK_BASE) {
        const int pid = bid - PACK_BASE;
        int ji = 0;
#pragma unroll
        for (int i = 1; i < 8; ++i) if (pid >= cfg.j[i].blk0) ji = i;
        const PackJob J = cfg.j[ji];
        int id = (pid - J.blk0) * 256 + tid;
        int n = NCT32 * J.KT * 64;
        if (id >= n) return;
        int lane = id & 63;
        int kt = (id >> 6) % J.KT;
        int ct = id / (J.KT * 64);
        int col = ct * 32 + (lane & 31);
        int kbase = kt * 16 + (lane >> 5) * 8;
        short8 v;
#pragma unroll
        for (int jj = 0; jj < 8; ++jj) {
            int k = kbase + jj;
            float f = (k < J.Kreal && col < HREAL) ? J.W[(size_t)k * HREAL + col] : 0.f;
            v[jj] = (short)f2bf(f);
        }
        J.dst[(size_t)(ct * J.KTfull + J.ktOff + kt) * 64 + lane] = v;
    } else {
        int id = (bid - PK_BASE) * 256 + tid;     // exact multiple (76800)
        u32 w = 0;
        if (cfg.mn[id]) w = 0x80000000u | ((u32)cfg.agp[id] << 16) | (u32)cfg.bgp[id];
        cfg.pk[id] = w;
    }
}

// ================= MFMA GEMM device core (32x32x16), W staged in LDS =================
// Block = 32*WAVES rows x 2 col-tiles. All waves share the 2-ct W panel, which is
// cooperatively burst into LDS once (coalesced, one barrier) -- removes the per-kt
// global-load latency chain that dominated the R4/R5 engine (W at point-of-use).
// A-loads chunked (<=10 live fragments). A = [A1 | A2] split at kt==KT1.
// ct<NCT32 -> out0 bf16; else out1 bf16 or out1f fp32.
// Epilogue: +bias (bias0/bias1, nullptr->0), +addp (fp32, ADDF), relu (RELU).
template<int KT, int KT1, int WAVES, bool RELU, bool OUT1F, bool ADDF>
__device__ __forceinline__ void gemm_dev(
    int bx, int by, int tid,
    const __hip_bfloat16* __restrict__ A1,
    const __hip_bfloat16* __restrict__ A2,
    const short8* __restrict__ Wp,
    const float* __restrict__ bias0,
    const float* __restrict__ bias1,
    __hip_bfloat16* __restrict__ out0,
    __hip_bfloat16* __restrict__ out1,
    float* __restrict__ out1f,
    const float* __restrict__ addp) {
    extern __shared__ short8 Wl[];             // [2*KT*64] : 2 ct panels
    const int lane = tid & 63;
    const int wv   = tid >> 6;                 // 0..WAVES-1
    const int m0   = bx * (32 * WAVES) + wv * 32;
    const int ct0  = by * 2;
    const int r1   = m0 + (lane & 31);
    const int koff = (lane >> 5) * 8;

    constexpr int S1  = KT1 * 16;
    constexpr int S2  = (KT - KT1) * 16;
    constexpr int CH  = (KT >= 10) ? 10 : KT;  // live A-fragment window
    constexpr int NCH = KT / CH;
    constexpr int NW  = 2 * KT * 64;           // short8 elements of W panel

    // ---- cooperative W panel stage: one coalesced burst + one barrier ----
    {
        const short8* wsrc = Wp + (size_t)ct0 * KT * 64;
#pragma unroll
        for (int i = 0; i < (NW + WAVES * 64 - 1) / (WAVES * 64); ++i) {
            const int idx = i * (WAVES * 64) + tid;
            if (NW % (WAVES * 64) == 0 || idx < NW) Wl[idx] = wsrc[idx];
        }
    }
    __syncthreads();

    f32x16 acc[2];
#pragma unroll
    for (int r = 0; r < 16; ++r) { acc[0][r] = 0.f; acc[1][r] = 0.f; }

    const short8* w0 = Wl + lane;              // LDS reads: lane-consecutive 16B, conflict-free
    const short8* w1 = Wl + KT * 64 + lane;

#pragma unroll
    for (int ch = 0; ch < NCH; ++ch) {
        short8 a[CH];
#pragma unroll
        for (int kt = 0; kt < CH; ++kt) {
            const int g = ch * CH + kt;
            if (g < KT1)
                a[kt] = *reinterpret_cast<const short8*>(A1 + (size_t)r1 * S1 + g * 16 + koff);
            else
                a[kt] = *reinterpret_cast<const short8*>(A2 + (size_t)r1 * S2 + (g - KT1) * 16 + koff);
        }
#pragma unroll
        for (int kt = 0; kt < CH; ++kt) {
            const int g = ch * CH + kt;
            acc[0] = __builtin_amdgcn_mfma_f32_32x32x16_bf16(a[kt], w0[g * 64], acc[0], 0, 0, 0);
            acc[1] = __builtin_amdgcn_mfma_f32_32x32x16_bf16(a[kt], w1[g * 64], acc[1], 0, 0, 0);
        }
    }

#pragma unroll
    for (int c = 0; c < 2; ++c) {
        const int ct = ct0 + c;
        const bool second = (ct >= NCT32);
        const int colb = second ? ct * 32 - HP : ct * 32;
        const int col = colb + (lane & 31);
        __hip_bfloat16* op = second ? out1 : out0;
        const float* bp = second ? bias1 : bias0;
        const float bb = (bp && col < HREAL) ? bp[col] : 0.f;
#pragma unroll
        for (int r = 0; r < 16; ++r) {
            const int row = m0 + (r & 3) + 8 * (r >> 2) + 4 * (lane >> 5);
            float v = acc[c][r] + bb;
            if (ADDF) v += addp[(size_t)row * HP + col];
            if (RELU) v = fmaxf(v, 0.f);
            if (second) {
                if (OUT1F) out1f[(size_t)row * HP + col] = v;
                else       out1[(size_t)row * HP + col] = __float2bfloat16(v);
            } else {
                op[(size_t)row * HP + col] = __float2bfloat16(v);
            }
        }
    }
}

// ---- input GEMMs: fc1 (600 2-wave blocks) + bond dual (2500 2-wave blocks) in one launch ----
#define FC1_BLKS  (MA/64 * 5)          // 600
#define BOND_BLKS (MB/64 * 10)         // 2500
#define INPUT_LDS (2 * 6 * 64 * 16)    // max(KT=6, KT=2) panel = 12288 B
__global__ __launch_bounds__(128)
void k_input_gemms(const __hip_bfloat16* __restrict__ A1b,
                   const __hip_bfloat16* __restrict__ bondb,
                   const short8* __restrict__ pW1,
                   const short8* __restrict__ pWbd,
                   const float* __restrict__ bgn,
                   __hip_bfloat16* __restrict__ af0,
                   __hip_bfloat16* __restrict__ bondgc,
                   __hip_bfloat16* __restrict__ bnb) {
    const int bid = blockIdx.x;
    if (bid < FC1_BLKS) {
        gemm_dev<6, 6, 2, true, false, false>(bid % (MA/64), bid / (MA/64), threadIdx.x,
                                              A1b, A1b, pW1, nullptr, nullptr, af0, nullptr, nullptr, nullptr);
    } else {
        const int b2 = bid - FC1_BLKS;
        gemm_dev<2, 2, 2, false, false, false>(b2 % (MB/64), b2 / (MB/64), threadIdx.x,
                                               bondb, bondb, pWbd, bgn, nullptr, bondgc, bnb, nullptr, nullptr);
    }
}

#define GEMM20_LDS (2 * 20 * 64 * 16)  // 40960 B -> 4 blocks/CU

// ---- per-iteration stage 1 (4-wave): Tb = af@W_nei  AND  U = af@W_gaTop + b_gc_atom (fp32) ----
__global__ __launch_bounds__(256)
void k_gemm_nu(const __hip_bfloat16* __restrict__ af, const short8* __restrict__ W,
               const float* __restrict__ bias1,
               __hip_bfloat16* __restrict__ Tb, float* __restrict__ U) {
    gemm_dev<20, 20, 4, false, true, false>(blockIdx.x, blockIdx.y, threadIdx.x,
                                            af, af, W, nullptr, bias1, Tb, nullptr, U, nullptr);
}

// ---- per-iteration stage 3 (4-wave): afn = relu(U + neib@W_gaBot) ----
__global__ __launch_bounds__(256)
void k_gemm_bot(const __hip_bfloat16* __restrict__ neib, const short8* __restrict__ W,
                const float* __restrict__ U, __hip_bfloat16* __restrict__ afn) {
    gemm_dev<20, 20, 4, true, false, true>(blockIdx.x, blockIdx.y, threadIdx.x,
                                           neib, neib, W, nullptr, nullptr, afn, nullptr, nullptr, U);
}

// ---- final dual GEMM (4-wave): selfF = af@W_fc2 (ct<10), A2f = af@W_fc2a (ct>=10) ----
__global__ __launch_bounds__(256)
void k_gemm_final(const __hip_bfloat16* __restrict__ af, const short8* __restrict__ W,
                  __hip_bfloat16* __restrict__ selfF, __hip_bfloat16* __restrict__ A2f) {
    gemm_dev<20, 20, 4, false, false, false>(blockIdx.x, blockIdx.y, threadIdx.x,
                                             af, af, W, nullptr, nullptr, selfF, A2f, nullptr, nullptr);
}

// ================= batch-LDS gather: nei = sum_j relu(T[ag] + bondgc[bg]) =================
// One block per (batch, col-eighth). Stage T[b,:,c0:c0+40u32] (9.6KB) + bondgc[b,:,same] (20KB)
// + pk (4.8KB) into LDS; all neighbor reads then hit LDS instead of scattered L2/L3.
#define GBLK (BATCH * 8)   // 512 blocks
__global__ __launch_bounds__(512)
void gather_lds(const u32* __restrict__ T,       // [MA][160]
                const u32* __restrict__ BG,      // [MB][160]
                const u32* __restrict__ pk,
                u32* __restrict__ nei) {
    extern __shared__ u32 sm[];
    u32* TL = sm;                 // [120][20]
    u32* BL = sm + 120 * 20;      // [250][20]
    u32* PL = BL + 250 * 20;      // [1200]
    const int b   = blockIdx.x >> 3;
    const int c0  = (blockIdx.x & 7) * 20;     // u32 col base within HP/2=160
    const int tid = threadIdx.x;

    for (int i = tid; i < 120 * 10; i += 512) {
        int r = i / 10, p = i - r * 10;
        *reinterpret_cast<u32x2*>(&TL[r * 20 + 2 * p]) =
            *reinterpret_cast<const u32x2*>(T + (size_t)(b * NATOM + r) * (HP / 2) + c0 + 2 * p);
    }
    for (int i = tid; i < 250 * 10; i += 512) {
        int r = i / 10, p = i - r * 10;
        *reinterpret_cast<u32x2*>(&BL[r * 20 + 2 * p]) =
            *reinterpret_cast<const u32x2*>(BG + (size_t)(b * NBOND + r) * (HP / 2) + c0 + 2 * p);
    }
    for (int i = tid; i < NATOM * NNB; i += 512) PL[i] = pk[b * NATOM * NNB + i];
    __syncthreads();

    for (int i = tid; i < 120 * 10; i += 512) {
        const int row = i / 10, p = i - row * 10;
        float lo0 = 0.f, hi0 = 0.f, lo1 = 0.f, hi1 = 0.f;
#pragma unroll
        for (int j = 0; j < NNB; ++j) {
            const u32 w = PL[row * NNB + j];
            if ((int)w < 0) {
                const int a  = (w >> 16) & 0xff;
                const int bo = w & 0xffff;
                u32x2 ta = *reinterpret_cast<const u32x2*>(&TL[a * 20 + 2 * p]);
                u32x2 tb = *reinterpret_cast<const u32x2*>(&BL[bo * 20 + 2 * p]);
                lo0 += fmaxf(bflo(ta[0]) + bflo(tb[0]), 0.f);
                hi0 += fmaxf(bfhi(ta[0]) + bfhi(tb[0]), 0.f);
                lo1 += fmaxf(bflo(ta[1]) + bflo(tb[1]), 0.f);
                hi1 += fmaxf(bfhi(ta[1]) + bfhi(tb[1]), 0.f);
            }
        }
        u32x2 o;
        o[0] = (u32)f2bf(lo0) | ((u32)f2bf(hi0) << 16);
        o[1] = (u32)f2bf(lo1) | ((u32)f2bf(hi1) << 16);
        *reinterpret_cast<u32x2*>(nei + (size_t)(b * NATOM + row) * (HP / 2) + c0 + 2 * p) = o;
    }
}
#define GATHER_LDS_BYTES ((120*20 + 250*20 + 1200) * 4)   // 34400

// ================= batch-LDS final: out = maska ? selfF * sum_j mask (A2f[ag]*bnb[bg]) : 0 =================
__global__ __launch_bounds__(512)
void final_lds(const u32* __restrict__ A2f,      // [MA][160]
               const u32* __restrict__ bnb,      // [MB][160]
               const u32* __restrict__ selfF,    // [MA][160]
               const u32* __restrict__ pk,
               const int* __restrict__ maska,
               float* __restrict__ out) {        // [MA][300] fp32
    extern __shared__ u32 sm[];
    u32* AL = sm;                 // [120][20]
    u32* BL = sm + 120 * 20;      // [250][20]
    u32* PL = BL + 250 * 20;      // [1200]
    u32* ML = PL + 1200;          // [120]
    const int b   = blockIdx.x >> 3;
    const int c0  = (blockIdx.x & 7) * 20;
    const int tid = threadIdx.x;

    for (int i = tid; i < 120 * 10; i += 512) {
        int r = i / 10, p = i - r * 10;
        *reinterpret_cast<u32x2*>(&AL[r * 20 + 2 * p]) =
            *reinterpret_cast<const u32x2*>(A2f + (size_t)(b * NATOM + r) * (HP / 2) + c0 + 2 * p);
    }
    for (int i = tid; i < 250 * 10; i += 512) {
        int r = i / 10, p = i - r * 10;
        *reinterpret_cast<u32x2*>(&BL[r * 20 + 2 * p]) =
            *reinterpret_cast<const u32x2*>(bnb + (size_t)(b * NBOND + r) * (HP / 2) + c0 + 2 * p);
    }
    for (int i = tid; i < NATOM * NNB; i += 512) PL[i] = pk[b * NATOM * NNB + i];
    for (int i = tid; i < NATOM; i += 512) ML[i] = (u32)(maska[b * NATOM + i] != 0);
    __syncthreads();

    for (int i = tid; i < 120 * 10; i += 512) {
        const int row = i / 10, p = i - row * 10;
        const int cA = c0 + 2 * p;               // global u32 col; valid out iff cA < 150
        if (cA >= 150) continue;
        float lo0 = 0.f, hi0 = 0.f, lo1 = 0.f, hi1 = 0.f;
#pragma unroll
        for (int j = 0; j < NNB; ++j) {
            const u32 w = PL[row * NNB + j];
            if ((int)w < 0) {
                const int a  = (w >> 16) & 0xff;
                const int bo = w & 0xffff;
                u32x2 va = *reinterpret_cast<const u32x2*>(&AL[a * 20 + 2 * p]);
                u32x2 vb = *reinterpret_cast<const u32x2*>(&BL[bo * 20 + 2 * p]);
                lo0 += bflo(va[0]) * bflo(vb[0]);
                hi0 += bfhi(va[0]) * bfhi(vb[0]);
                lo1 += bflo(va[1]) * bflo(vb[1]);
                hi1 += bfhi(va[1]) * bfhi(vb[1]);
            }
        }
        float4 r4 = make_float4(0.f, 0.f, 0.f, 0.f);
        if (ML[row]) {
            u32x2 s = *reinterpret_cast<const u32x2*>(selfF + (size_t)(b * NATOM + row) * (HP / 2) + cA);
            r4.x = bflo(s[0]) * lo0;
            r4.y = bfhi(s[0]) * hi0;
            r4.z = bflo(s[1]) * lo1;
            r4.w = bfhi(s[1]) * hi1;
        }
        *reinterpret_cast<float4*>(out + (size_t)(b * NATOM + row) * HREAL + 2 * cA) = r4;
    }
}
#define FINAL_LDS_BYTES ((120*20 + 250*20 + 1200 + 120) * 4)   // 34880

extern "C" void kernel_launch(void* const* d_in, const int* in_sizes, int n_in,
                              void* d_out, int out_size, void* d_ws, size_t ws_size,
                              hipStream_t stream) {
    const float* A1        = (const float*)d_in[0];
    const float* bond      = (const float*)d_in[1];
    const int*   ag        = (const int*)d_in[2];
    const int*   bg        = (const int*)d_in[3];
    const int*   maskn     = (const int*)d_in[6];
    const int*   maska     = (const int*)d_in[7];
    const float* W_fc1     = (const float*)d_in[8];
    const float* W_gc_nei  = (const float*)d_in[9];
    const float* b_gc_nei  = (const float*)d_in[10];
    const float* W_gc_atom = (const float*)d_in[11];
    const float* b_gc_atom = (const float*)d_in[12];
    const float* W_fc2a    = (const float*)d_in[13];
    const float* W_fc2b    = (const float*)d_in[14];
    const float* W_fc2     = (const float*)d_in[15];
    float* out = (float*)d_out;

    // ---- workspace carve-up ----
    char* p = (char*)d_ws;
    auto alloc = [&](size_t bytes) { char* r = p; p += (bytes + 63) & ~(size_t)63; return r; };
    __hip_bfloat16* A1b    = (__hip_bfloat16*)alloc((size_t)MA * 96 * 2);
    __hip_bfloat16* bondb  = (__hip_bfloat16*)alloc((size_t)MB * 32 * 2);
    __hip_bfloat16* af0    = (__hip_bfloat16*)alloc((size_t)MA * HP * 2);
    __hip_bfloat16* af1    = (__hip_bfloat16*)alloc((size_t)MA * HP * 2);
    __hip_bfloat16* Tb     = (__hip_bfloat16*)alloc((size_t)MA * HP * 2);
    __hip_bfloat16* neib   = (__hip_bfloat16*)alloc((size_t)MA * HP * 2);
    __hip_bfloat16* selfF  = (__hip_bfloat16*)alloc((size_t)MA * HP * 2);
    __hip_bfloat16* A2f    = (__hip_bfloat16*)alloc((size_t)MA * HP * 2);
    __hip_bfloat16* bondgc = (__hip_bfloat16*)alloc((size_t)MB * HP * 2);
    __hip_bfloat16* bnb    = (__hip_bfloat16*)alloc((size_t)MB * HP * 2);
    float*          U      = (float*)alloc((size_t)MA * HP * 4);        // fp32 af@W_gaTop + bias
    u32*            pk     = (u32*)alloc((size_t)MA * NNB * 4);         // packed nbr table
    short8* pW1  = (short8*)alloc((size_t)NCT32 * 6  * 64 * 16);        // fc1          K=96
    short8* pWnei= (short8*)alloc((size_t)2 * NCT32 * 20 * 64 * 16);    // nei | gaTop  K=320, 20 ct
    short8* pWgb = (short8*)alloc((size_t)NCT32 * 20 * 64 * 16);        // gaBot        K=320
    short8* pWbd = (short8*)alloc((size_t)2 * NCT32 * 2 * 64 * 16);     // bond dual    K=32, 20 ct
    short8* pWfd = (short8*)alloc((size_t)2 * NCT32 * 20 * 64 * 16);    // fc2 | fc2a   K=320, 20 ct

    // ---- prep: convs + packs + pk in one launch ----
    Prep cfg;
    cfg.a1src = A1;   cfg.a1dst = A1b;
    cfg.bsrc  = bond; cfg.bdst  = bondb;
    cfg.mn = maskn; cfg.agp = ag; cfg.bgp = bg; cfg.pk = pk;
    //           W                                  dst                          Kreal  KT KTf off blk0
    cfg.j[0] = { W_fc1,                             pW1,                         AFDIM, 6,  6,  0,   0 };
    cfg.j[1] = { W_gc_nei,                          pWnei,                       HREAL, 20, 20, 0,  15 };
    cfg.j[2] = { W_gc_atom,                         pWnei + (size_t)NCT32*20*64, HREAL, 20, 20, 0,  65 };
    cfg.j[3] = { W_gc_atom + (size_t)HREAL * HREAL, pWgb,                        HREAL, 20, 20, 0, 115 };
    cfg.j[4] = { W_gc_nei + (size_t)HREAL * HREAL,  pWbd,                        BFDIM, 2,  2,  0, 165 };
    cfg.j[5] = { W_fc2b,                            pWbd + (size_t)NCT32*2*64,   BFDIM, 2,  2,  0, 170 };
    cfg.j[6] = { W_fc2,                             pWfd,                        HREAL, 20, 20, 0, 175 };
    cfg.j[7] = { W_fc2a,                            pWfd + (size_t)NCT32*20*64,  HREAL, 20, 20, 0, 225 };
    prep_all<<<dim3(PREP_BLKS), dim3(256), 0, stream>>>(cfg);

    // ---- input GEMMs (fc1 + bond dual), 2-wave blocks, W staged in LDS ----
    k_input_gemms<<<dim3(FC1_BLKS + BOND_BLKS), dim3(128), INPUT_LDS, stream>>>(
        A1b, bondb, pW1, pWbd, b_gc_nei, af0, bondgc, bnb);

    const dim3 gNU(MA / 128, 10);   // (60,10) 4-wave dual: Tb + U
    const dim3 gBOT(MA / 128, 5);   // (60,5)  4-wave
    const dim3 t256(256), t512(512);

    // ---- graph-conv iterations ----
    const __hip_bfloat16* af = af0;
    __hip_bfloat16* afn = af1;
    for (int it = 0; it < 2; ++it) {
        k_gemm_nu<<<gNU, t256, GEMM20_LDS, stream>>>(af, pWnei, b_gc_atom, Tb, U);
        gather_lds<<<dim3(GBLK), t512, GATHER_LDS_BYTES, stream>>>(
            (const u32*)Tb, (const u32*)bondgc, pk, (u32*)neib);
        k_gemm_bot<<<gBOT, t256, GEMM20_LDS, stream>>>(neib, pWgb, U, afn);
        const __hip_bfloat16* t = afn; afn = (__hip_bfloat16*)af; af = t;
    }

    // ---- final layer ----
    k_gemm_final<<<gNU, t256, GEMM20_LDS, stream>>>(af, pWfd, selfF, A2f);
    final_lds<<<dim3(GBLK), t512, FINAL_LDS_BYTES, stream>>>(
        (const u32*)A2f, (const u32*)bnb, (const u32*)selfF, pk, maska, out);
}

// Round 7
// 130.491 us; speedup vs baseline: 3.8901x; 1.0317x over previous
//
#include <hip/hip_runtime.h>
#include <hip/hip_bf16.h>

// Problem constants
#define BATCH 64
#define NATOM 120
#define NNB 10
#define NBOND 250
#define AFDIM 82
#define BFDIM 6
#define HREAL 300
#define HP 320            // padded H (bf16 activation row stride); pad cols hold exact 0
#define NCT32 10          // 10 col-tiles of 32 -> 320
#define MA (BATCH*NATOM)  // 7680
#define MB (BATCH*NBOND)  // 16000

typedef short short8 __attribute__((ext_vector_type(8)));   // 8 bf16 (4 VGPRs)
typedef float f32x16 __attribute__((ext_vector_type(16)));  // 32x32 MFMA accumulator
typedef unsigned int u32;
typedef u32 u32x2 __attribute__((ext_vector_type(2)));
typedef unsigned short u16;

__device__ __forceinline__ float bflo(u32 v) { return __builtin_bit_cast(float, v << 16); }
__device__ __forceinline__ float bfhi(u32 v) { return __builtin_bit_cast(float, v & 0xffff0000u); }
__device__ __forceinline__ u16 f2bf(float f) {
    __hip_bfloat16 h = __float2bfloat16(f);
    return __builtin_bit_cast(u16, h);
}
__device__ __forceinline__ int imin(int a, int b) { return a < b ? a : b; }

// ================= prep: convs + weight packs + packed nbr table in ONE launch =================
struct PackJob { const float* W; short8* dst; int Kreal, KT, KTfull, ktOff, blk0; };
struct Prep {
    const float* a1src; __hip_bfloat16* a1dst;   // [MA][82] -> [MA][96]
    const float* bsrc;  __hip_bfloat16* bdst;    // [MB][6]  -> [MB][32]
    const int *mn, *agp, *bgp; u32* pk;          // packed nbr table [MA*NNB]
    PackJob j[8];
};

#define CONV1_BLKS 2880   // MA*96/256
#define CONV2_BLKS 2000   // MB*32/256
#define PACK_BASE  (CONV1_BLKS + CONV2_BLKS)
#define PACK_BLKS  275
#define PK_BASE    (PACK_BASE + PACK_BLKS)
#define PK_BLKS    300    // MA*NNB/256 = 76800/256
#define PREP_BLKS  (PK_BASE + PK_BLKS)   // 5455

__global__ __launch_bounds__(256) void prep_all(Prep cfg) {
    const int bid = blockIdx.x;
    const int tid = threadIdx.x;
    if (bid < CONV1_BLKS) {
        int id = bid * 256 + tid;                 // exact multiple
        int r = id / 96, c = id - r * 96;
        float f = (c < AFDIM) ? cfg.a1src[(size_t)r * AFDIM + c] : 0.f;
        cfg.a1dst[id] = __float2bfloat16(f);
    } else if (bid < PACK_BASE) {
        int id = (bid - CONV1_BLKS) * 256 + tid;  // exact multiple
        int r = id >> 5, c = id & 31;
        float f = (c < BFDIM) ? cfg.bsrc[(size_t)r * BFDIM + c] : 0.f;
        cfg.bdst[id] = __float2bfloat16(f);
    } else if (bid < PK_BASE) {
        const int pid = bid - PACK_BASE;
        int ji = 0;
#pragma unroll
        for (int i = 1; i < 8; ++i) if (pid >= cfg.j[i].blk0) ji = i;
        const PackJob J = cfg.j[ji];
        int id = (pid - J.blk0) * 256 + tid;
        int n = NCT32 * J.KT * 64;
        if (id >= n) return;
        int lane = id & 63;
        int kt = (id >> 6) % J.KT;
        int ct = id / (J.KT * 64);
        int col = ct * 32 + (lane & 31);
        int kbase = kt * 16 + (lane >> 5) * 8;
        short8 v;
#pragma unroll
        for (int jj = 0; jj < 8; ++jj) {
            int k = kbase + jj;
            float f = (k < J.Kreal && col < HREAL) ? J.W[(size_t)k * HREAL + col] : 0.f;
            v[jj] = (short)f2bf(f);
        }
        J.dst[(size_t)(ct * J.KTfull + J.ktOff + kt) * 64 + lane] = v;
    } else {
        int id = (bid - PK_BASE) * 256 + tid;     // exact multiple (76800)
        u32 w = 0;
        if (cfg.mn[id]) w = 0x80000000u | ((u32)cfg.agp[id] << 16) | (u32)cfg.bgp[id];
        cfg.pk[id] = w;
    }
}

// ================= generic MFMA GEMM device core (32x32x16), W staged in LDS =================
// Block = 32*WAVES rows x 2 col-tiles; waves share the LDS W panel (one burst + barrier).
template<int KT, int KT1, int WAVES, bool RELU>
__device__ __forceinline__ void gemm_dev(
    int bx, int by, int tid,
    const __hip_bfloat16* __restrict__ A1,
    const __hip_bfloat16* __restrict__ A2,
    const short8* __restrict__ Wp,
    const float* __restrict__ bias0,
    __hip_bfloat16* __restrict__ out0,
    __hip_bfloat16* __restrict__ out1) {
    extern __shared__ short8 Wl[];             // [2*KT*64]
    const int lane = tid & 63;
    const int wv   = tid >> 6;
    const int m0   = bx * (32 * WAVES) + wv * 32;
    const int ct0  = by * 2;
    const int r1   = m0 + (lane & 31);
    const int koff = (lane >> 5) * 8;

    constexpr int S1  = KT1 * 16;
    constexpr int S2  = (KT - KT1) * 16;
    constexpr int CH  = (KT >= 10) ? 10 : KT;
    constexpr int NCH = KT / CH;
    constexpr int NW  = 2 * KT * 64;

    {
        const short8* wsrc = Wp + (size_t)ct0 * KT * 64;
#pragma unroll
        for (int i = 0; i < (NW + WAVES * 64 - 1) / (WAVES * 64); ++i) {
            const int idx = i * (WAVES * 64) + tid;
            if (NW % (WAVES * 64) == 0 || idx < NW) Wl[idx] = wsrc[idx];
        }
    }
    __syncthreads();

    f32x16 acc[2];
#pragma unroll
    for (int r = 0; r < 16; ++r) { acc[0][r] = 0.f; acc[1][r] = 0.f; }

    const short8* w0 = Wl + lane;
    const short8* w1 = Wl + KT * 64 + lane;

#pragma unroll
    for (int ch = 0; ch < NCH; ++ch) {
        short8 a[CH];
#pragma unroll
        for (int kt = 0; kt < CH; ++kt) {
            const int g = ch * CH + kt;
            if (g < KT1)
                a[kt] = *reinterpret_cast<const short8*>(A1 + (size_t)r1 * S1 + g * 16 + koff);
            else
                a[kt] = *reinterpret_cast<const short8*>(A2 + (size_t)r1 * S2 + (g - KT1) * 16 + koff);
        }
#pragma unroll
        for (int kt = 0; kt < CH; ++kt) {
            const int g = ch * CH + kt;
            acc[0] = __builtin_amdgcn_mfma_f32_32x32x16_bf16(a[kt], w0[g * 64], acc[0], 0, 0, 0);
            acc[1] = __builtin_amdgcn_mfma_f32_32x32x16_bf16(a[kt], w1[g * 64], acc[1], 0, 0, 0);
        }
    }

#pragma unroll
    for (int c = 0; c < 2; ++c) {
        const int ct = ct0 + c;
        const bool second = (ct >= NCT32);
        const int colb = second ? ct * 32 - HP : ct * 32;
        const int col = colb + (lane & 31);
        __hip_bfloat16* op = second ? out1 : out0;
        const float bb = (!second && bias0 && col < HREAL) ? bias0[col] : 0.f;
#pragma unroll
        for (int r = 0; r < 16; ++r) {
            const int row = m0 + (r & 3) + 8 * (r >> 2) + 4 * (lane >> 5);
            float v = acc[c][r] + bb;
            if (RELU) v = fmaxf(v, 0.f);
            op[(size_t)row * HP + col] = __float2bfloat16(v);
        }
    }
}

// ---- input GEMMs: fc1 (600 2-wave blocks) + bond dual (2500 2-wave blocks) in one launch ----
#define FC1_BLKS  (MA/64 * 5)          // 600
#define BOND_BLKS (MB/64 * 10)         // 2500
#define INPUT_LDS (2 * 6 * 64 * 16)    // 12288 B
__global__ __launch_bounds__(128)
void k_input_gemms(const __hip_bfloat16* __restrict__ A1b,
                   const __hip_bfloat16* __restrict__ bondb,
                   const short8* __restrict__ pW1,
                   const short8* __restrict__ pWbd,
                   const float* __restrict__ bgn,
                   __hip_bfloat16* __restrict__ af0,
                   __hip_bfloat16* __restrict__ bondgc,
                   __hip_bfloat16* __restrict__ bnb) {
    const int bid = blockIdx.x;
    if (bid < FC1_BLKS) {
        gemm_dev<6, 6, 2, true>(bid % (MA/64), bid / (MA/64), threadIdx.x,
                                A1b, A1b, pW1, nullptr, af0, nullptr);
    } else {
        const int b2 = bid - FC1_BLKS;
        gemm_dev<2, 2, 2, false>(b2 % (MB/64), b2 / (MB/64), threadIdx.x,
                                 bondb, bondb, pWbd, bgn, bondgc, bnb);
    }
}

// ---- bot GEMM (R0-form K=640 concat): afn = relu([af|nei]@W_ga + b_ga), 80KB W panel -> 2 blk/CU ----
#define BOT_LDS (2 * 40 * 64 * 16)     // 81920 B
__global__ __launch_bounds__(256)
void k_gemm_bot(const __hip_bfloat16* __restrict__ af,
                const __hip_bfloat16* __restrict__ neib,
                const short8* __restrict__ W,
                const float* __restrict__ b_ga,
                __hip_bfloat16* __restrict__ afn) {
    gemm_dev<40, 20, 4, true>(blockIdx.x, blockIdx.y, threadIdx.x,
                              af, neib, W, b_ga, afn, nullptr);
}

// ================= fused nu-GEMM + gather, one block per (batch, 32-col tile) =================
// Computes T-slice = af[b]@W_nei[ct] straight into LDS (Tb never exists in global),
// then nei[b,:,32cols] = sum_j relu(T[ag] + bondgc[bg]) -> global.
#define NUG_LDS (20*64*16 + 120*32*2 + 250*32*2 + 1200*4)   // 20480+7680+16000+4800 = 48960
__global__ __launch_bounds__(256)
void k_nu_gather(const __hip_bfloat16* __restrict__ af,
                 const short8* __restrict__ pWnei,
                 const u32* __restrict__ bondgc,   // [MB][160]
                 const u32* __restrict__ pk,
                 u32* __restrict__ nei) {          // [MA][160]
    extern __shared__ char smraw[];
    short8* WL = (short8*)smraw;                       // [20*64]
    u16*    TL = (u16*)(smraw + 20480);                // [120][32]
    u16*    BLh = (u16*)(smraw + 20480 + 7680);        // [250][32]
    u32*    PL = (u32*)(smraw + 20480 + 7680 + 16000); // [1200]
    u32*    BL = (u32*)BLh;                            // u32 view [250][16]
    const int b   = blockIdx.x;
    const int ct  = blockIdx.y;
    const int tid = threadIdx.x;

    // ---- stage: W panel (1280 short8), bondgc slice (4000 u32), pk ----
    {
        const short8* wsrc = pWnei + (size_t)ct * 20 * 64;
#pragma unroll
        for (int i = 0; i < 5; ++i) WL[i * 256 + tid] = wsrc[i * 256 + tid];
    }
    for (int i = tid; i < 2000; i += 256) {           // u32x2 items
        int r = i >> 3, w = i & 7;
        *reinterpret_cast<u32x2*>(&BL[r * 16 + 2 * w]) =
            *reinterpret_cast<const u32x2*>(bondgc + (size_t)(b * NBOND + r) * (HP / 2) + ct * 16 + 2 * w);
    }
    for (int i = tid; i < NATOM * NNB; i += 256) PL[i] = pk[b * NATOM * NNB + i];
    __syncthreads();

    // ---- GEMM phase: 4 waves x 32 rows (clamped), K=320, 1 ct ----
    {
        const int lane = tid & 63;
        const int wv   = tid >> 6;
        const int r1   = imin(wv * 32 + (lane & 31), NATOM - 1);
        const int koff = (lane >> 5) * 8;
        const __hip_bfloat16* arow = af + (size_t)(b * NATOM + r1) * HP + koff;
        f32x16 acc;
#pragma unroll
        for (int r = 0; r < 16; ++r) acc[r] = 0.f;
        const short8* w0 = WL + lane;
#pragma unroll
        for (int ch = 0; ch < 2; ++ch) {
            short8 a[10];
#pragma unroll
            for (int kt = 0; kt < 10; ++kt)
                a[kt] = *reinterpret_cast<const short8*>(arow + (ch * 10 + kt) * 16);
#pragma unroll
            for (int kt = 0; kt < 10; ++kt)
                acc = __builtin_amdgcn_mfma_f32_32x32x16_bf16(a[kt], w0[(ch * 10 + kt) * 64], acc, 0, 0, 0);
        }
        const int col = lane & 31;
#pragma unroll
        for (int r = 0; r < 16; ++r) {
            const int row = wv * 32 + (r & 3) + 8 * (r >> 2) + 4 * (lane >> 5);
            if (row < NATOM) TL[row * 32 + col] = f2bf(acc[r]);
        }
    }
    __syncthreads();

    // ---- gather phase: 1920 (row, colpair) items ----
    for (int i = tid; i < NATOM * 16; i += 256) {
        const int row = i >> 4, cp = i & 15;
        float lo = 0.f, hi = 0.f;
#pragma unroll
        for (int j = 0; j < NNB; ++j) {
            const u32 w = PL[row * NNB + j];
            if ((int)w < 0) {
                const int a  = (w >> 16) & 0xff;
                const int bo = w & 0xffff;
                const u32 ta = *reinterpret_cast<const u32*>(&TL[a * 32 + 2 * cp]);
                const u32 tb = BL[bo * 16 + cp];
                lo += fmaxf(bflo(ta) + bflo(tb), 0.f);
                hi += fmaxf(bfhi(ta) + bfhi(tb), 0.f);
            }
        }
        nei[(size_t)(b * NATOM + row) * (HP / 2) + ct * 16 + cp] =
            (u32)f2bf(lo) | ((u32)f2bf(hi) << 16);
    }
}

// ================= fused final GEMM + product, one block per (batch, 32-col tile) =================
// selfF-slice = af@W_fc2[ct], A2f-slice = af@W_fc2a[ct] (both in LDS), then
// out = maska ? selfF * sum_j mask (A2f[ag]*bnb[bg]) : 0  (fp32, direct to output).
#define FIN_LDS (2*20*64*16 + 120*32*2 + 120*32*2 + 250*32*2 + 1200*4 + 120*4)  // 77600
__global__ __launch_bounds__(256)
void k_final_fused(const __hip_bfloat16* __restrict__ af,
                   const short8* __restrict__ pWfd,    // fc2 ct 0..9 | fc2a ct 10..19
                   const u32* __restrict__ bnb,        // [MB][160]
                   const u32* __restrict__ pk,
                   const int* __restrict__ maska,
                   float* __restrict__ out) {          // [MA][300]
    extern __shared__ char smraw[];
    short8* WL = (short8*)smraw;                              // [2*20*64]
    u16*    SL = (u16*)(smraw + 40960);                       // selfF [120][32]
    u16*    AL = (u16*)(smraw + 40960 + 7680);                // A2f   [120][32]
    u16*    BLh = (u16*)(smraw + 40960 + 2 * 7680);           // bnb   [250][32]
    u32*    PL = (u32*)(smraw + 40960 + 2 * 7680 + 16000);    // [1200]
    u32*    ML = PL + 1200;                                   // [120]
    u32*    BL = (u32*)BLh;
    const int b   = blockIdx.x;
    const int ct  = blockIdx.y;
    const int tid = threadIdx.x;

    // ---- stage: two W panels (2560 short8), bnb slice, pk, maska ----
    {
        const short8* w2  = pWfd + (size_t)ct * 20 * 64;          // fc2[ct]
        const short8* w2a = pWfd + (size_t)(NCT32 + ct) * 20 * 64;// fc2a[ct]
#pragma unroll
        for (int i = 0; i < 5; ++i) {
            WL[i * 256 + tid]        = w2[i * 256 + tid];
            WL[1280 + i * 256 + tid] = w2a[i * 256 + tid];
        }
    }
    for (int i = tid; i < 2000; i += 256) {
        int r = i >> 3, w = i & 7;
        *reinterpret_cast<u32x2*>(&BL[r * 16 + 2 * w]) =
            *reinterpret_cast<const u32x2*>(bnb + (size_t)(b * NBOND + r) * (HP / 2) + ct * 16 + 2 * w);
    }
    for (int i = tid; i < NATOM * NNB; i += 256) PL[i] = pk[b * NATOM * NNB + i];
    for (int i = tid; i < NATOM; i += 256) ML[i] = (u32)(maska[b * NATOM + i] != 0);
    __syncthreads();

    // ---- dual GEMM phase ----
    {
        const int lane = tid & 63;
        const int wv   = tid >> 6;
        const int r1   = imin(wv * 32 + (lane & 31), NATOM - 1);
        const int koff = (lane >> 5) * 8;
        const __hip_bfloat16* arow = af + (size_t)(b * NATOM + r1) * HP + koff;
        f32x16 acc0, acc1;
#pragma unroll
        for (int r = 0; r < 16; ++r) { acc0[r] = 0.f; acc1[r] = 0.f; }
        const short8* w0 = WL + lane;
        const short8* w1 = WL + 1280 + lane;
#pragma unroll
        for (int ch = 0; ch < 2; ++ch) {
            short8 a[10];
#pragma unroll
            for (int kt = 0; kt < 10; ++kt)
                a[kt] = *reinterpret_cast<const short8*>(arow + (ch * 10 + kt) * 16);
#pragma unroll
            for (int kt = 0; kt < 10; ++kt) {
                acc0 = __builtin_amdgcn_mfma_f32_32x32x16_bf16(a[kt], w0[(ch * 10 + kt) * 64], acc0, 0, 0, 0);
                acc1 = __builtin_amdgcn_mfma_f32_32x32x16_bf16(a[kt], w1[(ch * 10 + kt) * 64], acc1, 0, 0, 0);
            }
        }
        const int col = lane & 31;
#pragma unroll
        for (int r = 0; r < 16; ++r) {
            const int row = wv * 32 + (r & 3) + 8 * (r >> 2) + 4 * (lane >> 5);
            if (row < NATOM) {
                SL[row * 32 + col] = f2bf(acc0[r]);
                AL[row * 32 + col] = f2bf(acc1[r]);
            }
        }
    }
    __syncthreads();

    // ---- product phase: 1920 (row, colpair) items; guard col < 300 ----
    for (int i = tid; i < NATOM * 16; i += 256) {
        const int row = i >> 4, cp = i & 15;
        const int c = ct * 32 + 2 * cp;
        if (c >= HREAL) continue;
        float lo = 0.f, hi = 0.f;
#pragma unroll
        for (int j = 0; j < NNB; ++j) {
            const u32 w = PL[row * NNB + j];
            if ((int)w < 0) {
                const int a  = (w >> 16) & 0xff;
                const int bo = w & 0xffff;
                const u32 va = *reinterpret_cast<const u32*>(&AL[a * 32 + 2 * cp]);
                const u32 vb = BL[bo * 16 + cp];
                lo += bflo(va) * bflo(vb);
                hi += bfhi(va) * bfhi(vb);
            }
        }
        float2 r2;
        r2.x = 0.f; r2.y = 0.f;
        if (ML[row]) {
            const u32 s = *reinterpret_cast<const u32*>(&SL[row * 32 + 2 * cp]);
            r2.x = bflo(s) * lo;
            r2.y = bfhi(s) * hi;
        }
        *reinterpret_cast<float2*>(out + (size_t)(b * NATOM + row) * HREAL + c) = r2;
    }
}

extern "C" void kernel_launch(void* const* d_in, const int* in_sizes, int n_in,
                              void* d_out, int out_size, void* d_ws, size_t ws_size,
                              hipStream_t stream) {
    const float* A1        = (const float*)d_in[0];
    const float* bond      = (const float*)d_in[1];
    const int*   ag        = (const int*)d_in[2];
    const int*   bg        = (const int*)d_in[3];
    const int*   maskn     = (const int*)d_in[6];
    const int*   maska     = (const int*)d_in[7];
    const float* W_fc1     = (const float*)d_in[8];
    const float* W_gc_nei  = (const float*)d_in[9];
    const float* b_gc_nei  = (const float*)d_in[10];
    const float* W_gc_atom = (const float*)d_in[11];
    const float* b_gc_atom = (const float*)d_in[12];
    const float* W_fc2a    = (const float*)d_in[13];
    const float* W_fc2b    = (const float*)d_in[14];
    const float* W_fc2     = (const float*)d_in[15];
    float* out = (float*)d_out;

    // ---- workspace carve-up ----
    char* p = (char*)d_ws;
    auto alloc = [&](size_t bytes) { char* r = p; p += (bytes + 63) & ~(size_t)63; return r; };
    __hip_bfloat16* A1b    = (__hip_bfloat16*)alloc((size_t)MA * 96 * 2);
    __hip_bfloat16* bondb  = (__hip_bfloat16*)alloc((size_t)MB * 32 * 2);
    __hip_bfloat16* af0    = (__hip_bfloat16*)alloc((size_t)MA * HP * 2);
    __hip_bfloat16* af1    = (__hip_bfloat16*)alloc((size_t)MA * HP * 2);
    __hip_bfloat16* neib   = (__hip_bfloat16*)alloc((size_t)MA * HP * 2);
    __hip_bfloat16* bondgc = (__hip_bfloat16*)alloc((size_t)MB * HP * 2);
    __hip_bfloat16* bnb    = (__hip_bfloat16*)alloc((size_t)MB * HP * 2);
    u32*            pk     = (u32*)alloc((size_t)MA * NNB * 4);         // packed nbr table
    short8* pW1  = (short8*)alloc((size_t)NCT32 * 6  * 64 * 16);        // fc1          K=96
    short8* pWnei= (short8*)alloc((size_t)NCT32 * 20 * 64 * 16);        // gc_nei[:H]   K=320
    short8* pWga = (short8*)alloc((size_t)NCT32 * 40 * 64 * 16);        // gc_atom cat  K=640
    short8* pWbd = (short8*)alloc((size_t)2 * NCT32 * 2 * 64 * 16);     // bond dual    K=32, 20 ct
    short8* pWfd = (short8*)alloc((size_t)2 * NCT32 * 20 * 64 * 16);    // fc2 | fc2a   K=320, 20 ct

    // ---- prep: convs + packs + pk in one launch ----
    Prep cfg;
    cfg.a1src = A1;   cfg.a1dst = A1b;
    cfg.bsrc  = bond; cfg.bdst  = bondb;
    cfg.mn = maskn; cfg.agp = ag; cfg.bgp = bg; cfg.pk = pk;
    //           W                                  dst                          Kreal  KT KTf off blk0
    cfg.j[0] = { W_fc1,                             pW1,                         AFDIM, 6,  6,  0,   0 };
    cfg.j[1] = { W_gc_nei,                          pWnei,                       HREAL, 20, 20, 0,  15 };
    cfg.j[2] = { W_gc_atom,                         pWga,                        HREAL, 20, 40, 0,  65 };
    cfg.j[3] = { W_gc_atom + (size_t)HREAL * HREAL, pWga,                        HREAL, 20, 40, 20, 115 };
    cfg.j[4] = { W_gc_nei + (size_t)HREAL * HREAL,  pWbd,                        BFDIM, 2,  2,  0, 165 };
    cfg.j[5] = { W_fc2b,                            pWbd + (size_t)NCT32*2*64,   BFDIM, 2,  2,  0, 170 };
    cfg.j[6] = { W_fc2,                             pWfd,                        HREAL, 20, 20, 0, 175 };
    cfg.j[7] = { W_fc2a,                            pWfd + (size_t)NCT32*20*64,  HREAL, 20, 20, 0, 225 };
    prep_all<<<dim3(PREP_BLKS), dim3(256), 0, stream>>>(cfg);

    // ---- opt-in LDS sizes > 64 KB (host-side attribute set; R2 precedent: graph-capture safe) ----
    static int attr_done = 0;
    if (!attr_done) {
        hipFuncSetAttribute((const void*)k_gemm_bot,    hipFuncAttributeMaxDynamicSharedMemorySize, BOT_LDS);
        hipFuncSetAttribute((const void*)k_final_fused, hipFuncAttributeMaxDynamicSharedMemorySize, FIN_LDS);
        attr_done = 1;
    }

    // ---- input GEMMs (fc1 + bond dual), W staged in LDS ----
    k_input_gemms<<<dim3(FC1_BLKS + BOND_BLKS), dim3(128), INPUT_LDS, stream>>>(
        A1b, bondb, pW1, pWbd, b_gc_nei, af0, bondgc, bnb);

    const dim3 gNUG(BATCH, NCT32);  // (64,10) fused nu+gather
    const dim3 gBOT(MA / 128, 5);   // (60,5)  K=640 concat bot
    const dim3 t256(256);

    // ---- graph-conv iterations ----
    const __hip_bfloat16* af = af0;
    __hip_bfloat16* afn = af1;
    for (int it = 0; it < 2; ++it) {
        k_nu_gather<<<gNUG, t256, NUG_LDS, stream>>>(
            af, pWnei, (const u32*)bondgc, pk, (u32*)neib);
        k_gemm_bot<<<gBOT, t256, BOT_LDS, stream>>>(af, neib, pWga, b_gc_atom, afn);
        const __hip_bfloat16* t = afn; afn = (__hip_bfloat16*)af; af = t;
    }

    // ---- fused final layer ----
    k_final_fused<<<gNUG, t256, FIN_LDS, stream>>>(
        af, pWfd, (const u32*)bnb, pk, maska, out);
}